// Round 7
// baseline (136.365 us; speedup 1.0000x reference)
//
#include <hip/hip_runtime.h>
#include <hip/hip_bf16.h>
#include <cstdint>

namespace {

constexpr int NPIX = 12544;   // 4*56*56

typedef __attribute__((ext_vector_type(8))) short bf16x8;
typedef __attribute__((ext_vector_type(4))) float f32x4;
typedef __attribute__((ext_vector_type(16))) float f32x16;
typedef _Float16 h2 __attribute__((ext_vector_type(2)));

__device__ __forceinline__ float wsum(float v) {
#pragma unroll
  for (int m = 32; m; m >>= 1) v += __shfl_xor(v, m, 64);
  return v;
}

__device__ __forceinline__ uint16_t f2bf(float f) {
  uint32_t u = __builtin_bit_cast(uint32_t, f);
  u += 0x7fffu + ((u >> 16) & 1u);
  return (uint16_t)(u >> 16);
}
__device__ __forceinline__ uint32_t packbf(float a, float b) {
  return (uint32_t)f2bf(a) | ((uint32_t)f2bf(b) << 16);
}
__device__ __forceinline__ ushort f2h(float f) {
  _Float16 h = (_Float16)f;
  return __builtin_bit_cast(ushort, h);
}
__device__ __forceinline__ float bflo(uint32_t u) { return __builtin_bit_cast(float, u << 16); }
__device__ __forceinline__ float bfhi(uint32_t u) { return __builtin_bit_cast(float, u & 0xffff0000u); }

__device__ __forceinline__ float gelu_fast(float v) {
  float u = 0.7978845608028654f * (v + 0.044715f * v * v * v);
  float e = __expf(2.f * u);
  float th = 1.f - 2.f * __builtin_amdgcn_rcpf(e + 1.f);
  return 0.5f * v * (1.f + th);
}

// ---------------- Prep: convert+transpose all weights to bf16 ----------------
__global__ __launch_bounds__(256) void k_prep(
    const float* __restrict__ nqkv, const float* __restrict__ nproj,
    const float* __restrict__ nf1, const float* __restrict__ nf2,
    const float* __restrict__ gqkv, const float* __restrict__ gf1,
    const float* __restrict__ gf2, ushort* __restrict__ wT) {
  int t = blockIdx.x * 256 + threadIdx.x;
  if (t >= 201728) return;
  int i = t;
  if (i < 41472) {  // natQkvT [3][192][72]
    int br = i / 13824, r = i % 13824, n = r / 72, k = r % 72;
    wT[t] = k < 64 ? f2bf(nqkv[(br * 64 + k) * 192 + n]) : (ushort)0;
    return;
  }
  i -= 41472;
  if (i < 13824) {  // natProjT [3][64][72]
    int br = i / 4608, r = i % 4608, n = r / 72, k = r % 72;
    wT[t] = k < 64 ? f2bf(nproj[(br * 64 + k) * 64 + n]) : (ushort)0;
    return;
  }
  i -= 13824;
  if (i < 55296) {  // natF1T [3][256][72]
    int br = i / 18432, r = i % 18432, n = r / 72, k = r % 72;
    wT[t] = k < 64 ? f2bf(nf1[(br * 64 + k) * 256 + n]) : (ushort)0;
    return;
  }
  i -= 55296;
  if (i < 50688) {  // natF2T [3][64][264]
    int br = i / 16896, r = i % 16896, n = r / 264, k = r % 264;
    wT[t] = k < 256 ? f2bf(nf2[(br * 256 + k) * 64 + n]) : (ushort)0;
    return;
  }
  i -= 50688;
  if (i < 13824) {  // gaQkvT [192][72] (reserved)
    int n = i / 72, k = i % 72;
    wT[t] = k < 64 ? f2bf(gqkv[k * 192 + n]) : (ushort)0;
    return;
  }
  i -= 13824;
  if (i < 13824) {  // gaF1T [192][72]
    int n = i / 72, k = i % 72;
    wT[t] = k < 64 ? f2bf(gf1[k * 192 + n]) : (ushort)0;
    return;
  }
  i -= 13824;
  {  // gaF2T [64][200]
    int n = i / 200, k = i % 200;
    wT[t] = k < 192 ? f2bf(gf2[k * 64 + n]) : (ushort)0;
  }
}

// ---------------- Kernel 1: NAT LN1 + QKV GEMM via MFMA ----------------
// q -> f16 (pre-scaled), K/V -> f16 [pix][128]
__global__ __launch_bounds__(256) void k_nat_ln_qkv(
    const float* __restrict__ x, const float* __restrict__ ln_g,
    const float* __restrict__ ln_b, const ushort* __restrict__ wT,
    const float* __restrict__ qkv_b, ushort* __restrict__ qn,
    ushort* __restrict__ kvn) {
  __shared__ __align__(16) ushort sA[64 * 72];
  __shared__ __align__(16) ushort sB[192 * 72];
  int br = blockIdx.x / 196, grp = blockIdx.x % 196;
  int tid = threadIdx.x, lane = tid & 63, wid = tid >> 6;
  const uint4* srcB = (const uint4*)(wT + br * 13824);
  uint4* dstB = (uint4*)sB;
  for (int i = tid; i < 1728; i += 256) dstB[i] = srcB[i];
  float g = ln_g[br * 64 + lane], bb = ln_b[br * 64 + lane];
#pragma unroll
  for (int i = 0; i < 16; ++i) {
    int pl = wid * 16 + i;
    float v = x[(size_t)(grp * 64 + pl) * 256 + br * 64 + lane];
    float s1 = wsum(v), s2 = wsum(v * v);
    float m = s1 * (1.f / 64.f);
    float var = s2 * (1.f / 64.f) - m * m;
    sA[pl * 72 + lane] = f2bf((v - m) * rsqrtf(var + 1e-5f) * g + bb);
  }
  __syncthreads();
  int lr = lane & 15, lk = (lane >> 4) * 8;
  int m0 = wid * 16;
  bf16x8 a0 = *(const bf16x8*)&sA[(m0 + lr) * 72 + lk];
  bf16x8 a1 = *(const bf16x8*)&sA[(m0 + lr) * 72 + 32 + lk];
  int r0 = m0 + (lane >> 4) * 4;
#pragma unroll
  for (int nt = 0; nt < 12; ++nt) {
    int n0 = nt * 16;
    bf16x8 b0 = *(const bf16x8*)&sB[(n0 + lr) * 72 + lk];
    bf16x8 b1 = *(const bf16x8*)&sB[(n0 + lr) * 72 + 32 + lk];
    f32x4 acc = {0.f, 0.f, 0.f, 0.f};
    acc = __builtin_amdgcn_mfma_f32_16x16x32_bf16(a0, b0, acc, 0, 0, 0);
    acc = __builtin_amdgcn_mfma_f32_16x16x32_bf16(a1, b1, acc, 0, 0, 0);
    int col = n0 + lr;
    float bias = qkv_b[br * 192 + col];
    if (nt < 4) {
      ushort* op = qn + ((size_t)br * NPIX + grp * 64 + r0) * 64 + col;
#pragma unroll
      for (int r = 0; r < 4; ++r) op[r * 64] = f2h((acc[r] + bias) * 0.25f);
    } else {
      ushort* op = kvn + ((size_t)br * NPIX + grp * 64 + r0) * 128 + (col - 64);
#pragma unroll
      for (int r = 0; r < 4; ++r) op[r * 128] = f2h(acc[r] + bias);
    }
  }
}

// ---------------- Kernel 2: NAT attention, pixel-pair + packed f16 -------
// 128 threads: thread = (horizontal pixel pair, head). halo K/V in LDS.
__global__ __launch_bounds__(128) void k_nat_attn(
    const ushort* __restrict__ qn, const ushort* __restrict__ kvn,
    const float* __restrict__ rpb, ushort* __restrict__ att) {
  __shared__ __align__(16) ushort sKV[196 * 136];
  int bi = blockIdx.x;
  int br = bi / 196, rem = bi % 196;
  int b = rem / 49, t = rem % 49;
  int y0 = (t / 7) * 8, x0 = (t % 7) * 8;
  int hy = min(max(y0 - 3, 0), 42), hx = min(max(x0 - 3, 0), 42);
  int tid = threadIdx.x;
  const ushort* kvbase = kvn + ((size_t)br * NPIX + b * 3136) * 128;
  for (int i = tid; i < 3136; i += 128) {
    int p = i >> 4, c = i & 15;
    int py = p / 14, px = p % 14;
    int gp = (hy + py) * 56 + (hx + px);
    uint4 v = *(const uint4*)&kvbase[(size_t)gp * 128 + c * 8];
    *(uint4*)&sKV[p * 136 + c * 8] = v;
  }
  __syncthreads();
  int h = tid >> 5, pr = tid & 31;
  int ly = pr >> 2, pxc = (pr & 3) * 2;
  int y = y0 + ly;
  int xg0 = x0 + pxc, xg1 = xg0 + 1;
  int sy = min(max(y - 3, 0), 49);
  int sx0 = min(max(xg0 - 3, 0), 49), sx1 = min(max(xg1 - 3, 0), 49);
  int dx1 = sx1 - sx0;  // 0 or 1
  int by = sy - hy, bx = sx0 - hx;
  int gp0 = b * 3136 + y * 56 + xg0;
  const uint32_t* qp0 = (const uint32_t*)(qn + ((size_t)br * NPIX + gp0) * 64 + h * 16);
  h2 q0[8], q1[8];
#pragma unroll
  for (int i = 0; i < 8; ++i) q0[i] = __builtin_bit_cast(h2, qp0[i]);
#pragma unroll
  for (int i = 0; i < 8; ++i) q1[i] = __builtin_bit_cast(h2, qp0[i + 32]);
  const float* rp0 = rpb + (br * 4 + h) * 169 + (sy - y + 6) * 13 + (sx0 - xg0 + 6);
  const float* rp1 = rpb + (br * 4 + h) * 169 + (sy - y + 6) * 13 + (sx1 - xg1 + 6);
  float m0v = -1e30f, l0 = 0.f, m1v = -1e30f, l1 = 0.f;
  h2 acc0[8], acc1[8];
  h2 z = {(_Float16)0.f, (_Float16)0.f};
#pragma unroll
  for (int i = 0; i < 8; ++i) { acc0[i] = z; acc1[i] = z; }
  for (int a = 0; a < 7; ++a) {
    const uint32_t* krow = (const uint32_t*)&sKV[((by + a) * 14 + bx) * 136 + h * 16];
    for (int c = 0; c < 8; ++c) {
      const uint32_t* kp = krow + c * 68;
      h2 d0 = z, d1 = z;
#pragma unroll
      for (int i = 0; i < 8; ++i) {
        h2 kk = __builtin_bit_cast(h2, kp[i]);
        d0 = kk * q0[i] + d0;
        d1 = kk * q1[i] + d1;
      }
      if (c < 7) {
        float sd = (float)d0[0] + (float)d0[1] + rp0[a * 13 + c];
        if (sd > m0v) {
          float sc = __expf(m0v - sd);
          m0v = sd; l0 *= sc;
          h2 sc2 = {(_Float16)sc, (_Float16)sc};
#pragma unroll
          for (int i = 0; i < 8; ++i) acc0[i] = acc0[i] * sc2;
        }
        float p = __expf(sd - m0v);
        l0 += p;
        h2 p2 = {(_Float16)p, (_Float16)p};
#pragma unroll
        for (int i = 0; i < 8; ++i)
          acc0[i] = __builtin_bit_cast(h2, kp[32 + i]) * p2 + acc0[i];
      }
      int c1 = c - dx1;
      if (c1 >= 0 && c1 < 7) {
        float sd = (float)d1[0] + (float)d1[1] + rp1[a * 13 + c1];
        if (sd > m1v) {
          float sc = __expf(m1v - sd);
          m1v = sd; l1 *= sc;
          h2 sc2 = {(_Float16)sc, (_Float16)sc};
#pragma unroll
          for (int i = 0; i < 8; ++i) acc1[i] = acc1[i] * sc2;
        }
        float p = __expf(sd - m1v);
        l1 += p;
        h2 p2 = {(_Float16)p, (_Float16)p};
#pragma unroll
        for (int i = 0; i < 8; ++i)
          acc1[i] = __builtin_bit_cast(h2, kp[32 + i]) * p2 + acc1[i];
      }
    }
  }
  float inv0 = 1.f / l0, inv1 = 1.f / l1;
  uint32_t* op0 = (uint32_t*)(att + ((size_t)br * NPIX + gp0) * 64 + h * 16);
#pragma unroll
  for (int i = 0; i < 8; ++i)
    op0[i] = packbf((float)acc0[i][0] * inv0, (float)acc0[i][1] * inv0);
  uint32_t* op1 = op0 + 32;
#pragma unroll
  for (int i = 0; i < 8; ++i)
    op1[i] = packbf((float)acc1[i][0] * inv1, (float)acc1[i][1] * inv1);
}

// ---------------- Kernel 3: NAT proj + residual via MFMA ----------------
__global__ __launch_bounds__(256) void k_nat_proj(
    const ushort* __restrict__ att, const ushort* __restrict__ wT,
    const float* __restrict__ pb, const float* __restrict__ x,
    float* __restrict__ x1) {
  __shared__ __align__(16) ushort sA[64 * 72];
  __shared__ __align__(16) ushort sB[64 * 72];
  int br = blockIdx.x / 196, grp = blockIdx.x % 196;
  int tid = threadIdx.x, lane = tid & 63, wid = tid >> 6;
  const uint4* srcB = (const uint4*)(wT + 41472 + br * 4608);
  uint4* dstB = (uint4*)sB;
  for (int i = tid; i < 576; i += 256) dstB[i] = srcB[i];
  const uint4* srcA = (const uint4*)(att + ((size_t)br * NPIX + grp * 64) * 64);
  for (int i = tid; i < 512; i += 256) {
    int row = i >> 3, seg = i & 7;
    *(uint4*)&sA[row * 72 + seg * 8] = srcA[i];
  }
  __syncthreads();
  int lr = lane & 15, lk = (lane >> 4) * 8;
  int m0 = wid * 16;
  bf16x8 a0 = *(const bf16x8*)&sA[(m0 + lr) * 72 + lk];
  bf16x8 a1 = *(const bf16x8*)&sA[(m0 + lr) * 72 + 32 + lk];
  int r0 = m0 + (lane >> 4) * 4;
#pragma unroll
  for (int nt = 0; nt < 4; ++nt) {
    int n0 = nt * 16;
    bf16x8 b0 = *(const bf16x8*)&sB[(n0 + lr) * 72 + lk];
    bf16x8 b1 = *(const bf16x8*)&sB[(n0 + lr) * 72 + 32 + lk];
    f32x4 acc = {0.f, 0.f, 0.f, 0.f};
    acc = __builtin_amdgcn_mfma_f32_16x16x32_bf16(a0, b0, acc, 0, 0, 0);
    acc = __builtin_amdgcn_mfma_f32_16x16x32_bf16(a1, b1, acc, 0, 0, 0);
    int col = n0 + lr;
    float bias = pb[br * 64 + col];
#pragma unroll
    for (int r = 0; r < 4; ++r) {
      int pg = grp * 64 + r0 + r;
      x1[((size_t)br * NPIX + pg) * 64 + col] =
          acc[r] + bias + x[(size_t)pg * 256 + br * 64 + col];
    }
  }
}

// ---------------- Kernel 5: GA pool+LN + QKV GEMM -> qb/kb/vT ----
// grid 99: blocks 0..97 compute 32 tokens each; block 98 zero-pads n=784..799
__global__ __launch_bounds__(256) void k_ga_qkv(
    const float* __restrict__ x, const float* __restrict__ gw,
    const float* __restrict__ gb, const float* __restrict__ w,
    const float* __restrict__ bias, ushort* __restrict__ qb,
    ushort* __restrict__ kb, ushort* __restrict__ vT) {
  if (blockIdx.x == 98) {
    int t = threadIdx.x;
    for (int i = t; i < 4096; i += 256) {
      int bh = i >> 8, rem = i & 255;
      int n = 784 + (rem >> 4), d = rem & 15;
      qb[((size_t)bh * 800 + n) * 16 + d] = 0;
      kb[((size_t)bh * 800 + n) * 16 + d] = 0;
      vT[((size_t)bh * 16 + d) * 800 + n] = 0;
    }
    return;
  }
  __shared__ float sW[64 * 192];
  __shared__ float sB[192];
  __shared__ float sX[32][65];
  int grp = blockIdx.x;
  int tid = threadIdx.x, lane = tid & 63, wid = tid >> 6;
  for (int i = tid * 4; i < 64 * 192; i += 1024)
    *(float4*)&sW[i] = *(const float4*)&w[i];
  if (tid < 192) sB[tid] = bias[tid];
  // pooled LN inputs (fused former k_ga_pool)
  float gg = gw[lane], bb = gb[lane];
#pragma unroll
  for (int i = 0; i < 8; ++i) {
    int p = wid * 8 + i;
    int token = grp * 32 + p;
    int b = token / 784, rem2 = token % 784, hp = rem2 / 28, wp = rem2 % 28;
    float s = 0.f;
#pragma unroll
    for (int dy = 0; dy < 2; ++dy)
#pragma unroll
      for (int dxx = 0; dxx < 2; ++dxx) {
        int pix = b * 3136 + (hp * 2 + dy) * 56 + (wp * 2 + dxx);
        float v = x[(size_t)pix * 256 + 192 + lane];
        float s1 = wsum(v), s2 = wsum(v * v);
        float m = s1 * (1.f / 64.f);
        float var = s2 * (1.f / 64.f) - m * m;
        s += (v - m) * rsqrtf(var + 1e-5f) * gg + bb;
      }
    sX[p][lane] = 0.25f * s;
  }
  __syncthreads();
  int pl = tid >> 3, o0 = (tid & 7) * 24;
  float acc[24];
#pragma unroll
  for (int j = 0; j < 24; ++j) acc[j] = sB[o0 + j];
  for (int c = 0; c < 64; ++c) {
    float a = sX[pl][c];
    const float4* wr = (const float4*)&sW[c * 192 + o0];
#pragma unroll
    for (int j4 = 0; j4 < 6; ++j4) {
      float4 w4 = wr[j4];
      acc[4 * j4 + 0] = fmaf(a, w4.x, acc[4 * j4 + 0]);
      acc[4 * j4 + 1] = fmaf(a, w4.y, acc[4 * j4 + 1]);
      acc[4 * j4 + 2] = fmaf(a, w4.z, acc[4 * j4 + 2]);
      acc[4 * j4 + 3] = fmaf(a, w4.w, acc[4 * j4 + 3]);
    }
  }
  int token = grp * 32 + pl;
  int b = token / 784, nn = token % 784;
#pragma unroll
  for (int j = 0; j < 24; ++j) {
    int col = o0 + j;
    float v = acc[j];
    if (col < 64) {
      int h = col >> 4, d = col & 15;
      qb[((size_t)(b * 4 + h) * 800 + nn) * 16 + d] = f2bf(v * 0.25f);
    } else if (col < 128) {
      int c = col - 64, h = c >> 4, d = c & 15;
      kb[((size_t)(b * 4 + h) * 800 + nn) * 16 + d] = f2bf(v);
    } else {
      int c = col - 128, h = c >> 4, d = c & 15;
      vT[((size_t)(b * 4 + h) * 16 + d) * 800 + nn] = f2bf(v);
    }
  }
}

// ---------------- Kernel 6: GA attention via MFMA 32x32x16 ----------------
// 1 wave per (bh, q-tile of 32 rows); grid = 16*25 = 400 blocks x 64 thr
__global__ __launch_bounds__(64) void k_ga_attn(
    const ushort* __restrict__ qb, const ushort* __restrict__ kb,
    const ushort* __restrict__ vT, const float* __restrict__ x,
    float* __restrict__ x1g) {
  int wt = blockIdx.x;
  int bh = wt / 25, qt = wt % 25;
  int h = bh & 3, b = bh >> 2;
  int lane = threadIdx.x;
  int qrow = lane & 31, hi = lane >> 5;
  int dmod = lane & 15;
  const ushort* qbase = qb + (size_t)bh * 800 * 16;
  const ushort* kbase = kb + (size_t)bh * 800 * 16;
  const ushort* vbase = vT + (size_t)bh * 16 * 800 + (size_t)dmod * 800;
  bf16x8 qf = *(const bf16x8*)&qbase[(qt * 32 + qrow) * 16 + hi * 8];
  float m = -1e30f, l = 0.f;
  f32x16 acc_o;
#pragma unroll
  for (int r = 0; r < 16; ++r) acc_o[r] = 0.f;
  bf16x8 kf = *(const bf16x8*)&kbase[(0 + qrow) * 16 + hi * 8];
  bf16x8 vf0 = *(const bf16x8*)&vbase[0 + hi * 8];
  bf16x8 vf1 = *(const bf16x8*)&vbase[16 + hi * 8];
  for (int kt = 0; kt < 25; ++kt) {
    int nb = (kt < 24 ? kt + 1 : 24) * 32;
    bf16x8 nkf = *(const bf16x8*)&kbase[(nb + qrow) * 16 + hi * 8];
    bf16x8 nvf0 = *(const bf16x8*)&vbase[nb + hi * 8];
    bf16x8 nvf1 = *(const bf16x8*)&vbase[nb + 16 + hi * 8];
    f32x16 zero;
#pragma unroll
    for (int r = 0; r < 16; ++r) zero[r] = 0.f;
    f32x16 st = __builtin_amdgcn_mfma_f32_32x32x16_bf16(kf, qf, zero, 0, 0, 0);
    float s[16];
#pragma unroll
    for (int r = 0; r < 16; ++r) s[r] = st[r];
    if (kt == 24) {
#pragma unroll
      for (int r = 8; r < 16; ++r) s[r] = -1e30f;
    }
    float tm = s[0];
#pragma unroll
    for (int r = 1; r < 16; ++r) tm = fmaxf(tm, s[r]);
    tm = fmaxf(tm, __shfl_xor(tm, 32, 64));
    if (__any(tm > m + 8.f)) {
      float mn = fmaxf(m, tm);
      float sc = __expf(m - mn);
      l *= sc;
      m = mn;
#pragma unroll
      for (int r = 0; r < 16; ++r) {
        int row = (r & 3) + 4 * hi + 8 * (r >> 2);
        float scr = __shfl(sc, row, 64);
        acc_o[r] *= scr;
      }
    }
    uint32_t pk[8];
    float ps = 0.f;
#pragma unroll
    for (int i = 0; i < 8; ++i) {
      float p0 = __expf(s[2 * i] - m), p1 = __expf(s[2 * i + 1] - m);
      ps += p0 + p1;
      pk[i] = packbf(p0, p1);
    }
    l += ps;
#pragma unroll
    for (int t = 0; t < 2; ++t) {
      uint32_t c0 = pk[4 * t + 0], c1 = pk[4 * t + 1];
      uint32_t c2 = pk[4 * t + 2], c3 = pk[4 * t + 3];
      uint32_t b00 = __shfl((int)c0, qrow, 64), b02 = __shfl((int)c2, qrow, 64);
      uint32_t b10 = __shfl((int)c1, qrow, 64), b12 = __shfl((int)c3, qrow, 64);
      uint32_t b20 = __shfl((int)c0, qrow + 32, 64), b22 = __shfl((int)c2, qrow + 32, 64);
      uint32_t b30 = __shfl((int)c1, qrow + 32, 64), b32 = __shfl((int)c3, qrow + 32, 64);
      union { uint32_t u[4]; bf16x8 v; } pa;
      pa.u[0] = hi ? b02 : b00;
      pa.u[1] = hi ? b12 : b10;
      pa.u[2] = hi ? b22 : b20;
      pa.u[3] = hi ? b32 : b30;
      acc_o = __builtin_amdgcn_mfma_f32_32x32x16_bf16(pa.v, (t ? vf1 : vf0),
                                                      acc_o, 0, 0, 0);
    }
    kf = nkf; vf0 = nvf0; vf1 = nvf1;
  }
  l += __shfl_xor(l, 32, 64);
  float inv = 1.f / l;
#pragma unroll
  for (int r = 0; r < 16; ++r) {
    int row = (r & 3) + 4 * hi + 8 * (r >> 2);
    float invr = __shfl(inv, row, 64);
    int n = qt * 32 + row;
    if (n < 784 && qrow < 16) {
      float o = acc_o[r] * invr;
      int hp = n / 28, wp = n % 28;
      int ch = h * 16 + dmod;
#pragma unroll
      for (int dy = 0; dy < 2; ++dy)
#pragma unroll
        for (int dxx = 0; dxx < 2; ++dxx) {
          int pix = b * 3136 + (hp * 2 + dy) * 56 + (wp * 2 + dxx);
          x1g[(size_t)pix * 64 + ch] = x[(size_t)pix * 256 + 192 + ch] + o;
        }
    }
  }
}

// ---------------- Kernel 7: LN2 + MLP + residual via MFMA (64 px/block) ---
template <bool NAT>
__global__ __launch_bounds__(256) void k_mlp(
    const float* __restrict__ x1, const float* __restrict__ nat_ln2_g,
    const float* __restrict__ nat_ln2_b, const ushort* __restrict__ wT,
    const float* __restrict__ nat_f1b, const float* __restrict__ nat_f2b,
    const float* __restrict__ ga_ln2_g, const float* __restrict__ ga_ln2_b,
    const float* __restrict__ ga_f1b, const float* __restrict__ ga_f2b,
    float* __restrict__ out) {
  constexpr int H1 = NAT ? 256 : 192;
  constexpr int K2P = NAT ? 264 : 200;
  constexpr int KB = H1 / 32;
  constexpr int SW = NAT ? 256 * 72 : 192 * 72;
  __shared__ __align__(16) ushort sX[64 * 72];
  __shared__ __align__(16) ushort sH[64 * K2P];
  __shared__ __align__(16) ushort sW[SW];
  int br = NAT ? (int)(blockIdx.x / 196) : 3;
  int grp = blockIdx.x % 196;
  int tid = threadIdx.x, lane = tid & 63, wid = tid >> 6;
  const ushort* W1 = NAT ? wT + 55296 + br * 18432 : wT + 175104;
  const ushort* W2 = NAT ? wT + 110592 + br * 16896 : wT + 188928;
  const float* B1 = NAT ? nat_f1b + br * 256 : ga_f1b;
  const float* B2 = NAT ? nat_f2b + br * 64 : ga_f2b;
  const float* G = NAT ? nat_ln2_g + br * 64 : ga_ln2_g;
  const float* Bt = NAT ? nat_ln2_b + br * 64 : ga_ln2_b;
  const float* xin = x1 + ((size_t)br * NPIX + grp * 64) * 64;
  constexpr int NW1 = H1 * 9;
  for (int i = tid; i < NW1; i += 256) ((uint4*)sW)[i] = ((const uint4*)W1)[i];
  float g = G[lane], bb = Bt[lane];
#pragma unroll
  for (int i = 0; i < 16; ++i) {
    int pl = wid * 16 + i;
    float v = xin[pl * 64 + lane];
    float s1 = wsum(v), s2 = wsum(v * v);
    float m = s1 * (1.f / 64.f);
    float var = s2 * (1.f / 64.f) - m * m;
    sX[pl * 72 + lane] = f2bf((v - m) * rsqrtf(var + 1e-5f) * g + bb);
  }
  __syncthreads();
  int lr = lane & 15, lk = (lane >> 4) * 8;
  int mbase = (wid & 1) * 16;
  int r0 = (lane >> 4) * 4;
  bf16x8 a0[2], a1[2];
#pragma unroll
  for (int mh = 0; mh < 2; ++mh) {
    int m0 = mh * 32 + mbase;
    a0[mh] = *(const bf16x8*)&sX[(m0 + lr) * 72 + lk];
    a1[mh] = *(const bf16x8*)&sX[(m0 + lr) * 72 + 32 + lk];
  }
#pragma unroll
  for (int t2 = 0; t2 < H1 / 32; ++t2) {
    int n0 = ((wid >> 1) + 2 * t2) * 16;
    bf16x8 b0 = *(const bf16x8*)&sW[(n0 + lr) * 72 + lk];
    bf16x8 b1 = *(const bf16x8*)&sW[(n0 + lr) * 72 + 32 + lk];
    int col = n0 + lr;
    float b1v = B1[col];
#pragma unroll
    for (int mh = 0; mh < 2; ++mh) {
      f32x4 acc = {0.f, 0.f, 0.f, 0.f};
      acc = __builtin_amdgcn_mfma_f32_16x16x32_bf16(a0[mh], b0, acc, 0, 0, 0);
      acc = __builtin_amdgcn_mfma_f32_16x16x32_bf16(a1[mh], b1, acc, 0, 0, 0);
      int m0 = mh * 32 + mbase;
#pragma unroll
      for (int r = 0; r < 4; ++r)
        sH[(m0 + r0 + r) * K2P + col] = f2bf(gelu_fast(acc[r] + b1v));
    }
  }
  __syncthreads();
  constexpr int NW2 = 64 * K2P / 8;
  for (int i = tid; i < NW2; i += 256) ((uint4*)sW)[i] = ((const uint4*)W2)[i];
  __syncthreads();
#pragma unroll
  for (int mh = 0; mh < 2; ++mh) {
    int m0 = mh * 32 + mbase;
    bf16x8 af[KB];
#pragma unroll
    for (int kb = 0; kb < KB; ++kb)
      af[kb] = *(const bf16x8*)&sH[(m0 + lr) * K2P + kb * 32 + lk];
#pragma unroll
    for (int u = 0; u < 2; ++u) {
      int n0 = ((wid >> 1) + 2 * u) * 16;
      f32x4 acc = {0.f, 0.f, 0.f, 0.f};
#pragma unroll
      for (int kb = 0; kb < KB; ++kb) {
        bf16x8 bf = *(const bf16x8*)&sW[(n0 + lr) * K2P + kb * 32 + lk];
        acc = __builtin_amdgcn_mfma_f32_16x16x32_bf16(af[kb], bf, acc, 0, 0, 0);
      }
      int col = n0 + lr;
      float b2v = B2[col];
#pragma unroll
      for (int r = 0; r < 4; ++r) {
        int p = m0 + r0 + r;
        int pix = grp * 64 + p;
        out[(size_t)pix * 256 + br * 64 + col] = xin[p * 64 + col] + acc[r] + b2v;
      }
    }
  }
}

}  // namespace

extern "C" void kernel_launch(void* const* d_in, const int* in_sizes, int n_in,
                              void* d_out, int out_size, void* d_ws, size_t ws_size,
                              hipStream_t stream) {
  const float* x = (const float*)d_in[0];
  const float* nat_ln1_g = (const float*)d_in[1];
  const float* nat_ln1_b = (const float*)d_in[2];
  const float* nat_qkv_w = (const float*)d_in[3];
  const float* nat_qkv_b = (const float*)d_in[4];
  const float* nat_rpb = (const float*)d_in[5];
  const float* nat_proj_w = (const float*)d_in[6];
  const float* nat_proj_b = (const float*)d_in[7];
  const float* nat_ln2_g = (const float*)d_in[8];
  const float* nat_ln2_b = (const float*)d_in[9];
  const float* nat_fc1_w = (const float*)d_in[10];
  const float* nat_fc1_b = (const float*)d_in[11];
  const float* nat_fc2_w = (const float*)d_in[12];
  const float* nat_fc2_b = (const float*)d_in[13];
  const float* ga_ln1_g = (const float*)d_in[14];
  const float* ga_ln1_b = (const float*)d_in[15];
  const float* ga_qkv_w = (const float*)d_in[16];
  const float* ga_qkv_b = (const float*)d_in[17];
  const float* ga_ln2_g = (const float*)d_in[18];
  const float* ga_ln2_b = (const float*)d_in[19];
  const float* ga_fc1_w = (const float*)d_in[20];
  const float* ga_fc1_b = (const float*)d_in[21];
  const float* ga_fc2_w = (const float*)d_in[22];
  const float* ga_fc2_b = (const float*)d_in[23];

  uint8_t* w8 = (uint8_t*)d_ws;
  ushort* qn     = (ushort*)w8;                       //  4,816,896 B (f16)
  ushort* kvn    = (ushort*)(w8 + 4816896);           //  9,633,792 B (f16)
  ushort* att    = (ushort*)(w8 + 14450688);          //  4,816,896 B (bf16)
  float*  x1     = (float*)(w8 + 19267584);           // 12,845,056 B
  ushort* wT     = (ushort*)(w8 + 32112640);          //    403,456 B
  ushort* qgb    = (ushort*)(w8 + 32516096);          //    409,600 B
  ushort* kgb    = (ushort*)(w8 + 32925696);          //    409,600 B
  ushort* vgT    = (ushort*)(w8 + 33335296);          //    409,600 B
  // total ~33.7 MB

  k_prep<<<dim3(789), dim3(256), 0, stream>>>(nat_qkv_w, nat_proj_w, nat_fc1_w,
                                              nat_fc2_w, ga_qkv_w, ga_fc1_w,
                                              ga_fc2_w, wT);
  k_nat_ln_qkv<<<dim3(588), dim3(256), 0, stream>>>(x, nat_ln1_g, nat_ln1_b, wT,
                                                    nat_qkv_b, qn, kvn);
  k_ga_qkv<<<dim3(99), dim3(256), 0, stream>>>(x, ga_ln1_g, ga_ln1_b, ga_qkv_w,
                                               ga_qkv_b, qgb, kgb, vgT);
  k_nat_attn<<<dim3(588), dim3(128), 0, stream>>>(qn, kvn, nat_rpb, att);
  k_nat_proj<<<dim3(588), dim3(256), 0, stream>>>(att, wT, nat_proj_b, x, x1);
  k_ga_attn<<<dim3(400), dim3(64), 0, stream>>>(qgb, kgb, vgT, x,
                                                x1 + (size_t)3 * NPIX * 64);
  k_mlp<true><<<dim3(588), dim3(256), 0, stream>>>(
      x1, nat_ln2_g, nat_ln2_b, wT, nat_fc1_b, nat_fc2_b, ga_ln2_g, ga_ln2_b,
      ga_fc1_b, ga_fc2_b, (float*)d_out);
  k_mlp<false><<<dim3(196), dim3(256), 0, stream>>>(
      x1, nat_ln2_g, nat_ln2_b, wT, nat_fc1_b, nat_fc2_b, ga_ln2_g, ga_ln2_b,
      ga_fc1_b, ga_fc2_b, (float*)d_out);
}

// Round 8
// 99.673 us; speedup vs baseline: 1.3681x; 1.3681x over previous
//
#include <hip/hip_runtime.h>
#include <hip/hip_bf16.h>
#include <cstdint>

namespace {

constexpr int NPIX = 12544;   // 4*56*56

typedef __attribute__((ext_vector_type(8))) short bf16x8;
typedef __attribute__((ext_vector_type(4))) float f32x4;
typedef __attribute__((ext_vector_type(16))) float f32x16;
typedef _Float16 h2 __attribute__((ext_vector_type(2)));

__device__ __forceinline__ float wsum(float v) {
#pragma unroll
  for (int m = 32; m; m >>= 1) v += __shfl_xor(v, m, 64);
  return v;
}

__device__ __forceinline__ uint16_t f2bf(float f) {
  uint32_t u = __builtin_bit_cast(uint32_t, f);
  u += 0x7fffu + ((u >> 16) & 1u);
  return (uint16_t)(u >> 16);
}
__device__ __forceinline__ uint32_t packbf(float a, float b) {
  return (uint32_t)f2bf(a) | ((uint32_t)f2bf(b) << 16);
}
__device__ __forceinline__ ushort f2h(float f) {
  _Float16 h = (_Float16)f;
  return __builtin_bit_cast(ushort, h);
}

__device__ __forceinline__ float gelu_fast(float v) {
  float u = 0.7978845608028654f * (v + 0.044715f * v * v * v);
  float e = __expf(2.f * u);
  float th = 1.f - 2.f * __builtin_amdgcn_rcpf(e + 1.f);
  return 0.5f * v * (1.f + th);
}

// ---------------- Prep: convert+transpose all weights to bf16 ----------------
__global__ __launch_bounds__(256) void k_prep(
    const float* __restrict__ nqkv, const float* __restrict__ nproj,
    const float* __restrict__ nf1, const float* __restrict__ nf2,
    const float* __restrict__ gqkv, const float* __restrict__ gf1,
    const float* __restrict__ gf2, ushort* __restrict__ wT) {
  int t = blockIdx.x * 256 + threadIdx.x;
  if (t >= 201728) return;
  int i = t;
  if (i < 41472) {
    int br = i / 13824, r = i % 13824, n = r / 72, k = r % 72;
    wT[t] = k < 64 ? f2bf(nqkv[(br * 64 + k) * 192 + n]) : (ushort)0;
    return;
  }
  i -= 41472;
  if (i < 13824) {
    int br = i / 4608, r = i % 4608, n = r / 72, k = r % 72;
    wT[t] = k < 64 ? f2bf(nproj[(br * 64 + k) * 64 + n]) : (ushort)0;
    return;
  }
  i -= 13824;
  if (i < 55296) {
    int br = i / 18432, r = i % 18432, n = r / 72, k = r % 72;
    wT[t] = k < 64 ? f2bf(nf1[(br * 64 + k) * 256 + n]) : (ushort)0;
    return;
  }
  i -= 55296;
  if (i < 50688) {
    int br = i / 16896, r = i % 16896, n = r / 264, k = r % 264;
    wT[t] = k < 256 ? f2bf(nf2[(br * 256 + k) * 64 + n]) : (ushort)0;
    return;
  }
  i -= 50688;
  if (i < 13824) {
    int n = i / 72, k = i % 72;
    wT[t] = k < 64 ? f2bf(gqkv[k * 192 + n]) : (ushort)0;
    return;
  }
  i -= 13824;
  if (i < 13824) {
    int n = i / 72, k = i % 72;
    wT[t] = k < 64 ? f2bf(gf1[k * 192 + n]) : (ushort)0;
    return;
  }
  i -= 13824;
  {
    int n = i / 200, k = i % 200;
    wT[t] = k < 192 ? f2bf(gf2[k * 64 + n]) : (ushort)0;
  }
}

// ---------------- Kernel A: fused QKV — NAT (0..587) | GA (588..636) | pad (637)
__global__ __launch_bounds__(256) void k_qkv(
    const float* __restrict__ x, const float* __restrict__ nat_ln1_g,
    const float* __restrict__ nat_ln1_b, const ushort* __restrict__ wT,
    const float* __restrict__ nat_qkv_b, ushort* __restrict__ qn,
    ushort* __restrict__ kvn, const float* __restrict__ ga_ln1_g,
    const float* __restrict__ ga_ln1_b, const float* __restrict__ ga_qkv_b,
    ushort* __restrict__ qb, ushort* __restrict__ kb, ushort* __restrict__ vT) {
  __shared__ __align__(16) ushort sA[64 * 72];
  __shared__ __align__(16) ushort sB[192 * 72];
  int bid = blockIdx.x;
  int tid = threadIdx.x, lane = tid & 63, wid = tid >> 6;
  if (bid == 637) {
    for (int i = tid; i < 4096; i += 256) {
      int bh = i >> 8, rem = i & 255;
      int n = 784 + (rem >> 4), d = rem & 15;
      qb[((size_t)bh * 800 + n) * 16 + d] = 0;
      kb[((size_t)bh * 800 + n) * 16 + d] = 0;
      vT[((size_t)bh * 16 + d) * 800 + n] = 0;
    }
    return;
  }
  int lr = lane & 15, lk = (lane >> 4) * 8;
  if (bid < 588) {  // NAT LN1 + QKV
    int br = bid / 196, grp = bid % 196;
    const uint4* srcB = (const uint4*)(wT + br * 13824);
    for (int i = tid; i < 1728; i += 256) ((uint4*)sB)[i] = srcB[i];
    float g = nat_ln1_g[br * 64 + lane], bb = nat_ln1_b[br * 64 + lane];
#pragma unroll
    for (int i = 0; i < 16; ++i) {
      int pl = wid * 16 + i;
      float v = x[(size_t)(grp * 64 + pl) * 256 + br * 64 + lane];
      float s1 = wsum(v), s2 = wsum(v * v);
      float m = s1 * (1.f / 64.f);
      float var = s2 * (1.f / 64.f) - m * m;
      sA[pl * 72 + lane] = f2bf((v - m) * rsqrtf(var + 1e-5f) * g + bb);
    }
    __syncthreads();
    int m0 = wid * 16;
    bf16x8 a0 = *(const bf16x8*)&sA[(m0 + lr) * 72 + lk];
    bf16x8 a1 = *(const bf16x8*)&sA[(m0 + lr) * 72 + 32 + lk];
    int r0 = m0 + (lane >> 4) * 4;
#pragma unroll
    for (int nt = 0; nt < 12; ++nt) {
      int n0 = nt * 16;
      bf16x8 b0 = *(const bf16x8*)&sB[(n0 + lr) * 72 + lk];
      bf16x8 b1 = *(const bf16x8*)&sB[(n0 + lr) * 72 + 32 + lk];
      f32x4 acc = {0.f, 0.f, 0.f, 0.f};
      acc = __builtin_amdgcn_mfma_f32_16x16x32_bf16(a0, b0, acc, 0, 0, 0);
      acc = __builtin_amdgcn_mfma_f32_16x16x32_bf16(a1, b1, acc, 0, 0, 0);
      int col = n0 + lr;
      float bias = nat_qkv_b[br * 192 + col];
      if (nt < 4) {
        ushort* op = qn + ((size_t)br * NPIX + grp * 64 + r0) * 64 + col;
#pragma unroll
        for (int r = 0; r < 4; ++r) op[r * 64] = f2h((acc[r] + bias) * 0.25f);
      } else {
        ushort* op = kvn + ((size_t)br * NPIX + grp * 64 + r0) * 128 + (col - 64);
#pragma unroll
        for (int r = 0; r < 4; ++r) op[r * 128] = f2h(acc[r] + bias);
      }
    }
  } else {  // GA pool+LN + QKV via MFMA (49 blocks x 64 tokens)
    int g64 = bid - 588;
    const uint4* srcB = (const uint4*)(wT + 161280);
    for (int i = tid; i < 1728; i += 256) ((uint4*)sB)[i] = srcB[i];
    float gg = ga_ln1_g[lane], bb = ga_ln1_b[lane];
#pragma unroll
    for (int i = 0; i < 16; ++i) {
      int tl = wid * 16 + i;
      int token = g64 * 64 + tl;
      int b = token / 784, rem2 = token % 784, hp = rem2 / 28, wp = rem2 % 28;
      float s = 0.f;
#pragma unroll
      for (int dy = 0; dy < 2; ++dy)
#pragma unroll
        for (int dxx = 0; dxx < 2; ++dxx) {
          int pix = b * 3136 + (hp * 2 + dy) * 56 + (wp * 2 + dxx);
          float v = x[(size_t)pix * 256 + 192 + lane];
          float s1 = wsum(v), s2 = wsum(v * v);
          float m = s1 * (1.f / 64.f);
          float var = s2 * (1.f / 64.f) - m * m;
          s += (v - m) * rsqrtf(var + 1e-5f) * gg + bb;
        }
      sA[tl * 72 + lane] = f2bf(0.25f * s);
    }
    __syncthreads();
    int m0 = wid * 16;
    bf16x8 a0 = *(const bf16x8*)&sA[(m0 + lr) * 72 + lk];
    bf16x8 a1 = *(const bf16x8*)&sA[(m0 + lr) * 72 + 32 + lk];
    int r0 = m0 + (lane >> 4) * 4;
#pragma unroll
    for (int nt = 0; nt < 12; ++nt) {
      int n0 = nt * 16;
      bf16x8 b0 = *(const bf16x8*)&sB[(n0 + lr) * 72 + lk];
      bf16x8 b1 = *(const bf16x8*)&sB[(n0 + lr) * 72 + 32 + lk];
      f32x4 acc = {0.f, 0.f, 0.f, 0.f};
      acc = __builtin_amdgcn_mfma_f32_16x16x32_bf16(a0, b0, acc, 0, 0, 0);
      acc = __builtin_amdgcn_mfma_f32_16x16x32_bf16(a1, b1, acc, 0, 0, 0);
      int col = n0 + lr;
      float bias = ga_qkv_b[col];
      int hh = (col & 63) >> 4, d = col & 15;
#pragma unroll
      for (int r = 0; r < 4; ++r) {
        int token = g64 * 64 + r0 + r;
        int b = token / 784, nn = token % 784;
        float v = acc[r] + bias;
        if (col < 64)
          qb[((size_t)(b * 4 + hh) * 800 + nn) * 16 + d] = f2bf(v * 0.25f);
        else if (col < 128)
          kb[((size_t)(b * 4 + hh) * 800 + nn) * 16 + d] = f2bf(v);
        else
          vT[((size_t)(b * 4 + hh) * 16 + d) * 800 + nn] = f2bf(v);
      }
    }
  }
}

// ---------------- Kernel B: fused attention ----------------
__global__ __launch_bounds__(256) void k_attn(
    const ushort* __restrict__ qn, const ushort* __restrict__ kvn,
    const float* __restrict__ rpb, const ushort* __restrict__ wT,
    const float* __restrict__ pb, const float* __restrict__ x,
    float* __restrict__ x1, const ushort* __restrict__ qb,
    const ushort* __restrict__ kb, const ushort* __restrict__ vT,
    float* __restrict__ x1g) {
  __shared__ __align__(16) ushort sKV[196 * 136];
  __shared__ __align__(16) ushort sAp[64 * 72];
  __shared__ __align__(16) ushort sWp[64 * 72];
  int bid = blockIdx.x;
  int tid = threadIdx.x, lane = tid & 63, wid = tid >> 6;
  if (bid < 588) {
    // NAT attention (f16 packed) + proj + residual
    int br = bid / 196, rem = bid % 196;
    int b = rem / 49, t = rem % 49;
    int y0 = (t / 7) * 8, x0 = (t % 7) * 8;
    int hy = min(max(y0 - 3, 0), 42), hx = min(max(x0 - 3, 0), 42);
    const ushort* kvbase = kvn + ((size_t)br * NPIX + b * 3136) * 128;
    for (int i = tid; i < 3136; i += 256) {
      int p = i >> 4, c = i & 15;
      int py = p / 14, px = p % 14;
      int gp = (hy + py) * 56 + (hx + px);
      uint4 v = *(const uint4*)&kvbase[(size_t)gp * 128 + c * 8];
      *(uint4*)&sKV[p * 136 + c * 8] = v;
    }
    const uint4* srcW = (const uint4*)(wT + 41472 + br * 4608);
    for (int i = tid; i < 576; i += 256) ((uint4*)sWp)[i] = srcW[i];
    __syncthreads();
    int pl = tid & 63, h = tid >> 6;
    int ly = pl >> 3, lx = pl & 7;
    int y = y0 + ly, xg = x0 + lx;
    int sy = min(max(y - 3, 0), 49), sx = min(max(xg - 3, 0), 49);
    int by = sy - hy, bx = sx - hx;
    int gpix = b * 3136 + y * 56 + xg;
    const uint32_t* qp = (const uint32_t*)(qn + ((size_t)br * NPIX + gpix) * 64 + h * 16);
    h2 q[8];
#pragma unroll
    for (int i = 0; i < 8; ++i) q[i] = __builtin_bit_cast(h2, qp[i]);
    const float* rp = rpb + (br * 4 + h) * 169 + (sy - y + 6) * 13 + (sx - xg + 6);
    float m = -1e30f, l = 0.f;
    h2 acc[8];
    h2 z = {(_Float16)0.f, (_Float16)0.f};
#pragma unroll
    for (int i = 0; i < 8; ++i) acc[i] = z;
    for (int a = 0; a < 7; ++a) {
      const uint32_t* krow = (const uint32_t*)&sKV[((by + a) * 14 + bx) * 136 + h * 16];
      for (int c = 0; c < 7; ++c) {
        const uint32_t* kp = krow + c * 68;
        h2 d = z;
#pragma unroll
        for (int i = 0; i < 8; ++i)
          d = __builtin_bit_cast(h2, kp[i]) * q[i] + d;
        float sd = (float)d[0] + (float)d[1] + rp[a * 13 + c];
        if (sd > m) {
          float sc = __expf(m - sd);
          m = sd; l *= sc;
          h2 sc2 = {(_Float16)sc, (_Float16)sc};
#pragma unroll
          for (int i = 0; i < 8; ++i) acc[i] = acc[i] * sc2;
        }
        float p = __expf(sd - m);
        l += p;
        h2 p2 = {(_Float16)p, (_Float16)p};
#pragma unroll
        for (int i = 0; i < 8; ++i)
          acc[i] = __builtin_bit_cast(h2, kp[32 + i]) * p2 + acc[i];
      }
    }
    float inv = 1.f / l;
    uint32_t* ao = (uint32_t*)&sAp[pl * 72 + h * 16];
#pragma unroll
    for (int i = 0; i < 8; ++i)
      ao[i] = packbf((float)acc[i][0] * inv, (float)acc[i][1] * inv);
    __syncthreads();
    int lr = lane & 15, lk = (lane >> 4) * 8;
    int m0 = wid * 16;
    bf16x8 a0 = *(const bf16x8*)&sAp[(m0 + lr) * 72 + lk];
    bf16x8 a1 = *(const bf16x8*)&sAp[(m0 + lr) * 72 + 32 + lk];
    int r0 = m0 + (lane >> 4) * 4;
#pragma unroll
    for (int nt = 0; nt < 4; ++nt) {
      int n0 = nt * 16;
      bf16x8 b0 = *(const bf16x8*)&sWp[(n0 + lr) * 72 + lk];
      bf16x8 b1 = *(const bf16x8*)&sWp[(n0 + lr) * 72 + 32 + lk];
      f32x4 oacc = {0.f, 0.f, 0.f, 0.f};
      oacc = __builtin_amdgcn_mfma_f32_16x16x32_bf16(a0, b0, oacc, 0, 0, 0);
      oacc = __builtin_amdgcn_mfma_f32_16x16x32_bf16(a1, b1, oacc, 0, 0, 0);
      int col = n0 + lr;
      float bias = pb[br * 64 + col];
#pragma unroll
      for (int r = 0; r < 4; ++r) {
        int rr = r0 + r;
        int gp2 = b * 3136 + (y0 + (rr >> 3)) * 56 + (x0 + (rr & 7));
        x1[((size_t)br * NPIX + gp2) * 64 + col] =
            oacc[r] + bias + x[(size_t)gp2 * 256 + br * 64 + col];
      }
    }
  } else {
    // GA attention: wave = q-tile
    int wt = (bid - 588) * 4 + wid;
    int bh = wt / 25, qt = wt % 25;
    int h = bh & 3, b = bh >> 2;
    int qrow = lane & 31, hi = lane >> 5;
    int dmod = lane & 15;
    const ushort* qbase = qb + (size_t)bh * 800 * 16;
    const ushort* kbase = kb + (size_t)bh * 800 * 16;
    const ushort* vbase = vT + (size_t)bh * 16 * 800 + (size_t)dmod * 800;
    bf16x8 qf = *(const bf16x8*)&qbase[(qt * 32 + qrow) * 16 + hi * 8];
    float m = -1e30f, l = 0.f;
    f32x16 acc_o;
#pragma unroll
    for (int r = 0; r < 16; ++r) acc_o[r] = 0.f;
    bf16x8 kf = *(const bf16x8*)&kbase[(0 + qrow) * 16 + hi * 8];
    bf16x8 vf0 = *(const bf16x8*)&vbase[0 + hi * 8];
    bf16x8 vf1 = *(const bf16x8*)&vbase[16 + hi * 8];
    for (int kt = 0; kt < 25; ++kt) {
      int nb = (kt < 24 ? kt + 1 : 24) * 32;
      bf16x8 nkf = *(const bf16x8*)&kbase[(nb + qrow) * 16 + hi * 8];
      bf16x8 nvf0 = *(const bf16x8*)&vbase[nb + hi * 8];
      bf16x8 nvf1 = *(const bf16x8*)&vbase[nb + 16 + hi * 8];
      f32x16 zero;
#pragma unroll
      for (int r = 0; r < 16; ++r) zero[r] = 0.f;
      f32x16 st = __builtin_amdgcn_mfma_f32_32x32x16_bf16(kf, qf, zero, 0, 0, 0);
      float s[16];
#pragma unroll
      for (int r = 0; r < 16; ++r) s[r] = st[r];
      if (kt == 24) {
#pragma unroll
        for (int r = 8; r < 16; ++r) s[r] = -1e30f;
      }
      float tm = s[0];
#pragma unroll
      for (int r = 1; r < 16; ++r) tm = fmaxf(tm, s[r]);
      tm = fmaxf(tm, __shfl_xor(tm, 32, 64));
      if (__any(tm > m + 8.f)) {
        float mn = fmaxf(m, tm);
        float sc = __expf(m - mn);
        l *= sc;
        m = mn;
#pragma unroll
        for (int r = 0; r < 16; ++r) {
          int row = (r & 3) + 4 * hi + 8 * (r >> 2);
          float scr = __shfl(sc, row, 64);
          acc_o[r] *= scr;
        }
      }
      uint32_t pk[8];
      float ps = 0.f;
#pragma unroll
      for (int i = 0; i < 8; ++i) {
        float p0 = __expf(s[2 * i] - m), p1 = __expf(s[2 * i + 1] - m);
        ps += p0 + p1;
        pk[i] = packbf(p0, p1);
      }
      l += ps;
#pragma unroll
      for (int t = 0; t < 2; ++t) {
        uint32_t c0 = pk[4 * t + 0], c1 = pk[4 * t + 1];
        uint32_t c2 = pk[4 * t + 2], c3 = pk[4 * t + 3];
        uint32_t b00 = __shfl((int)c0, qrow, 64), b02 = __shfl((int)c2, qrow, 64);
        uint32_t b10 = __shfl((int)c1, qrow, 64), b12 = __shfl((int)c3, qrow, 64);
        uint32_t b20 = __shfl((int)c0, qrow + 32, 64), b22 = __shfl((int)c2, qrow + 32, 64);
        uint32_t b30 = __shfl((int)c1, qrow + 32, 64), b32 = __shfl((int)c3, qrow + 32, 64);
        union { uint32_t u[4]; bf16x8 v; } pa;
        pa.u[0] = hi ? b02 : b00;
        pa.u[1] = hi ? b12 : b10;
        pa.u[2] = hi ? b22 : b20;
        pa.u[3] = hi ? b32 : b30;
        acc_o = __builtin_amdgcn_mfma_f32_32x32x16_bf16(pa.v, (t ? vf1 : vf0),
                                                        acc_o, 0, 0, 0);
      }
      kf = nkf; vf0 = nvf0; vf1 = nvf1;
    }
    l += __shfl_xor(l, 32, 64);
    float inv = 1.f / l;
#pragma unroll
    for (int r = 0; r < 16; ++r) {
      int row = (r & 3) + 4 * hi + 8 * (r >> 2);
      float invr = __shfl(inv, row, 64);
      int n = qt * 32 + row;
      if (n < 784 && qrow < 16) {
        float o = acc_o[r] * invr;
        int hp = n / 28, wp = n % 28;
        int ch = h * 16 + dmod;
#pragma unroll
        for (int dy = 0; dy < 2; ++dy)
#pragma unroll
          for (int dxx = 0; dxx < 2; ++dxx) {
            int pix = b * 3136 + (hp * 2 + dy) * 56 + (wp * 2 + dxx);
            x1g[(size_t)pix * 64 + ch] = x[(size_t)pix * 256 + 192 + ch] + o;
          }
      }
    }
  }
}

// ---------------- Kernel C: fused MLP ----------------
template <bool NAT>
__device__ __forceinline__ void mlp_body(
    int br, int grp, ushort* sX, ushort* sH, ushort* sW,
    const float* __restrict__ x1, const ushort* __restrict__ W1,
    const ushort* __restrict__ W2, const float* __restrict__ B1,
    const float* __restrict__ B2, const float* __restrict__ G,
    const float* __restrict__ Bt, float* __restrict__ out) {
  constexpr int H1 = NAT ? 256 : 192;
  constexpr int K2P = NAT ? 264 : 200;
  constexpr int KB = H1 / 32;
  int tid = threadIdx.x, lane = tid & 63, wid = tid >> 6;
  const float* xin = x1 + ((size_t)br * NPIX + grp * 64) * 64;
  constexpr int NW1 = H1 * 9;
  for (int i = tid; i < NW1; i += 256) ((uint4*)sW)[i] = ((const uint4*)W1)[i];
  float g = G[lane], bb = Bt[lane];
#pragma unroll
  for (int i = 0; i < 16; ++i) {
    int pl = wid * 16 + i;
    float v = xin[pl * 64 + lane];
    float s1 = wsum(v), s2 = wsum(v * v);
    float m = s1 * (1.f / 64.f);
    float var = s2 * (1.f / 64.f) - m * m;
    sX[pl * 72 + lane] = f2bf((v - m) * rsqrtf(var + 1e-5f) * g + bb);
  }
  __syncthreads();
  int lr = lane & 15, lk = (lane >> 4) * 8;
  int mbase = (wid & 1) * 16;
  int r0 = (lane >> 4) * 4;
  bf16x8 a0[2], a1[2];
#pragma unroll
  for (int mh = 0; mh < 2; ++mh) {
    int m0 = mh * 32 + mbase;
    a0[mh] = *(const bf16x8*)&sX[(m0 + lr) * 72 + lk];
    a1[mh] = *(const bf16x8*)&sX[(m0 + lr) * 72 + 32 + lk];
  }
#pragma unroll
  for (int t2 = 0; t2 < H1 / 32; ++t2) {
    int n0 = ((wid >> 1) + 2 * t2) * 16;
    bf16x8 b0 = *(const bf16x8*)&sW[(n0 + lr) * 72 + lk];
    bf16x8 b1 = *(const bf16x8*)&sW[(n0 + lr) * 72 + 32 + lk];
    int col = n0 + lr;
    float b1v = B1[col];
#pragma unroll
    for (int mh = 0; mh < 2; ++mh) {
      f32x4 acc = {0.f, 0.f, 0.f, 0.f};
      acc = __builtin_amdgcn_mfma_f32_16x16x32_bf16(a0[mh], b0, acc, 0, 0, 0);
      acc = __builtin_amdgcn_mfma_f32_16x16x32_bf16(a1[mh], b1, acc, 0, 0, 0);
      int m0 = mh * 32 + mbase;
#pragma unroll
      for (int r = 0; r < 4; ++r)
        sH[(m0 + r0 + r) * K2P + col] = f2bf(gelu_fast(acc[r] + b1v));
    }
  }
  __syncthreads();
  constexpr int NW2 = 64 * K2P / 8;
  for (int i = tid; i < NW2; i += 256) ((uint4*)sW)[i] = ((const uint4*)W2)[i];
  __syncthreads();
#pragma unroll
  for (int mh = 0; mh < 2; ++mh) {
    int m0 = mh * 32 + mbase;
    bf16x8 af[KB];
#pragma unroll
    for (int kb = 0; kb < KB; ++kb)
      af[kb] = *(const bf16x8*)&sH[(m0 + lr) * K2P + kb * 32 + lk];
#pragma unroll
    for (int u = 0; u < 2; ++u) {
      int n0 = ((wid >> 1) + 2 * u) * 16;
      f32x4 acc = {0.f, 0.f, 0.f, 0.f};
#pragma unroll
      for (int kb = 0; kb < KB; ++kb) {
        bf16x8 bf = *(const bf16x8*)&sW[(n0 + lr) * K2P + kb * 32 + lk];
        acc = __builtin_amdgcn_mfma_f32_16x16x32_bf16(af[kb], bf, acc, 0, 0, 0);
      }
      int col = n0 + lr;
      float b2v = B2[col];
#pragma unroll
      for (int r = 0; r < 4; ++r) {
        int p = m0 + r0 + r;
        int pix = grp * 64 + p;
        out[(size_t)pix * 256 + br * 64 + col] = xin[p * 64 + col] + acc[r] + b2v;
      }
    }
  }
}

__global__ __launch_bounds__(256) void k_mlp(
    const float* __restrict__ x1, const float* __restrict__ nat_ln2_g,
    const float* __restrict__ nat_ln2_b, const ushort* __restrict__ wT,
    const float* __restrict__ nat_f1b, const float* __restrict__ nat_f2b,
    const float* __restrict__ ga_ln2_g, const float* __restrict__ ga_ln2_b,
    const float* __restrict__ ga_f1b, const float* __restrict__ ga_f2b,
    float* __restrict__ out) {
  __shared__ __align__(16) ushort sX[64 * 72];
  __shared__ __align__(16) ushort sH[64 * 264];
  __shared__ __align__(16) ushort sW[256 * 72];
  int bid = blockIdx.x;
  if (bid < 588) {
    int br = bid / 196, grp = bid % 196;
    mlp_body<true>(br, grp, sX, sH, sW, x1, wT + 55296 + br * 18432,
                   wT + 110592 + br * 16896, nat_f1b + br * 256,
                   nat_f2b + br * 64, nat_ln2_g + br * 64, nat_ln2_b + br * 64,
                   out);
  } else {
    int grp = bid - 588;
    mlp_body<false>(3, grp, sX, sH, sW, x1, wT + 175104, wT + 188928, ga_f1b,
                    ga_f2b, ga_ln2_g, ga_ln2_b, out);
  }
}

}  // namespace

extern "C" void kernel_launch(void* const* d_in, const int* in_sizes, int n_in,
                              void* d_out, int out_size, void* d_ws, size_t ws_size,
                              hipStream_t stream) {
  const float* x = (const float*)d_in[0];
  const float* nat_ln1_g = (const float*)d_in[1];
  const float* nat_ln1_b = (const float*)d_in[2];
  const float* nat_qkv_w = (const float*)d_in[3];
  const float* nat_qkv_b = (const float*)d_in[4];
  const float* nat_rpb = (const float*)d_in[5];
  const float* nat_proj_w = (const float*)d_in[6];
  const float* nat_proj_b = (const float*)d_in[7];
  const float* nat_ln2_g = (const float*)d_in[8];
  const float* nat_ln2_b = (const float*)d_in[9];
  const float* nat_fc1_w = (const float*)d_in[10];
  const float* nat_fc1_b = (const float*)d_in[11];
  const float* nat_fc2_w = (const float*)d_in[12];
  const float* nat_fc2_b = (const float*)d_in[13];
  const float* ga_ln1_g = (const float*)d_in[14];
  const float* ga_ln1_b = (const float*)d_in[15];
  const float* ga_qkv_w = (const float*)d_in[16];
  const float* ga_qkv_b = (const float*)d_in[17];
  const float* ga_ln2_g = (const float*)d_in[18];
  const float* ga_ln2_b = (const float*)d_in[19];
  const float* ga_fc1_w = (const float*)d_in[20];
  const float* ga_fc1_b = (const float*)d_in[21];
  const float* ga_fc2_w = (const float*)d_in[22];
  const float* ga_fc2_b = (const float*)d_in[23];

  uint8_t* w8 = (uint8_t*)d_ws;
  ushort* qn  = (ushort*)w8;                  //  4,816,896 B (f16)
  ushort* kvn = (ushort*)(w8 + 4816896);      //  9,633,792 B (f16)
  float*  x1  = (float*)(w8 + 14450688);      // 12,845,056 B
  ushort* wT  = (ushort*)(w8 + 27295744);     //    403,456 B
  ushort* qgb = (ushort*)(w8 + 27699200);     //    409,600 B
  ushort* kgb = (ushort*)(w8 + 28108800);     //    409,600 B
  ushort* vgT = (ushort*)(w8 + 28518400);     //    409,600 B
  // total ~28.9 MB

  k_prep<<<dim3(789), dim3(256), 0, stream>>>(nat_qkv_w, nat_proj_w, nat_fc1_w,
                                              nat_fc2_w, ga_qkv_w, ga_fc1_w,
                                              ga_fc2_w, wT);
  k_qkv<<<dim3(638), dim3(256), 0, stream>>>(x, nat_ln1_g, nat_ln1_b, wT,
                                             nat_qkv_b, qn, kvn, ga_ln1_g,
                                             ga_ln1_b, ga_qkv_b, qgb, kgb, vgT);
  k_attn<<<dim3(688), dim3(256), 0, stream>>>(qn, kvn, nat_rpb, wT, nat_proj_b,
                                              x, x1, qgb, kgb, vgT,
                                              x1 + (size_t)3 * NPIX * 64);
  k_mlp<<<dim3(784), dim3(256), 0, stream>>>(x1, nat_ln2_g, nat_ln2_b, wT,
                                             nat_fc1_b, nat_fc2_b, ga_ln2_g,
                                             ga_ln2_b, ga_fc1_b, ga_fc2_b,
                                             (float*)d_out);
}

// Round 9
// 90.604 us; speedup vs baseline: 1.5051x; 1.1001x over previous
//
#include <hip/hip_runtime.h>
#include <hip/hip_bf16.h>
#include <cstdint>

namespace {

constexpr int NPIX = 12544;   // 4*56*56

typedef __attribute__((ext_vector_type(8))) short bf16x8;
typedef __attribute__((ext_vector_type(4))) float f32x4;
typedef __attribute__((ext_vector_type(16))) float f32x16;
typedef _Float16 h2 __attribute__((ext_vector_type(2)));

__device__ __forceinline__ float wsum(float v) {
#pragma unroll
  for (int m = 32; m; m >>= 1) v += __shfl_xor(v, m, 64);
  return v;
}

__device__ __forceinline__ uint16_t f2bf(float f) {
  uint32_t u = __builtin_bit_cast(uint32_t, f);
  u += 0x7fffu + ((u >> 16) & 1u);
  return (uint16_t)(u >> 16);
}
__device__ __forceinline__ uint32_t packbf(float a, float b) {
  return (uint32_t)f2bf(a) | ((uint32_t)f2bf(b) << 16);
}
__device__ __forceinline__ ushort f2h(float f) {
  _Float16 h = (_Float16)f;
  return __builtin_bit_cast(ushort, h);
}
__device__ __forceinline__ h2 bch2(uint32_t u) { return __builtin_bit_cast(h2, u); }

__device__ __forceinline__ float gelu_fast(float v) {
  float u = 0.7978845608028654f * (v + 0.044715f * v * v * v);
  float e = __expf(2.f * u);
  float th = 1.f - 2.f * __builtin_amdgcn_rcpf(e + 1.f);
  return 0.5f * v * (1.f + th);
}

// ---------------- Prep: convert+transpose all weights to bf16 ----------------
__global__ __launch_bounds__(256) void k_prep(
    const float* __restrict__ nqkv, const float* __restrict__ nproj,
    const float* __restrict__ nf1, const float* __restrict__ nf2,
    const float* __restrict__ gqkv, const float* __restrict__ gf1,
    const float* __restrict__ gf2, ushort* __restrict__ wT) {
  int t = blockIdx.x * 256 + threadIdx.x;
  if (t >= 201728) return;
  int i = t;
  if (i < 41472) {
    int br = i / 13824, r = i % 13824, n = r / 72, k = r % 72;
    wT[t] = k < 64 ? f2bf(nqkv[(br * 64 + k) * 192 + n]) : (ushort)0;
    return;
  }
  i -= 41472;
  if (i < 13824) {
    int br = i / 4608, r = i % 4608, n = r / 72, k = r % 72;
    wT[t] = k < 64 ? f2bf(nproj[(br * 64 + k) * 64 + n]) : (ushort)0;
    return;
  }
  i -= 13824;
  if (i < 55296) {
    int br = i / 18432, r = i % 18432, n = r / 72, k = r % 72;
    wT[t] = k < 64 ? f2bf(nf1[(br * 64 + k) * 256 + n]) : (ushort)0;
    return;
  }
  i -= 55296;
  if (i < 50688) {
    int br = i / 16896, r = i % 16896, n = r / 264, k = r % 264;
    wT[t] = k < 256 ? f2bf(nf2[(br * 256 + k) * 64 + n]) : (ushort)0;
    return;
  }
  i -= 50688;
  if (i < 13824) {
    int n = i / 72, k = i % 72;
    wT[t] = k < 64 ? f2bf(gqkv[k * 192 + n]) : (ushort)0;
    return;
  }
  i -= 13824;
  if (i < 13824) {
    int n = i / 72, k = i % 72;
    wT[t] = k < 64 ? f2bf(gf1[k * 192 + n]) : (ushort)0;
    return;
  }
  i -= 13824;
  {
    int n = i / 200, k = i % 200;
    wT[t] = k < 192 ? f2bf(gf2[k * 64 + n]) : (ushort)0;
  }
}

// ---------------- Kernel A: fused QKV — NAT (0..587) | GA (588..636) | pad (637)
__global__ __launch_bounds__(256) void k_qkv(
    const float* __restrict__ x, const float* __restrict__ nat_ln1_g,
    const float* __restrict__ nat_ln1_b, const ushort* __restrict__ wT,
    const float* __restrict__ nat_qkv_b, ushort* __restrict__ qn,
    ushort* __restrict__ kvn, const float* __restrict__ ga_ln1_g,
    const float* __restrict__ ga_ln1_b, const float* __restrict__ ga_qkv_b,
    ushort* __restrict__ qb, ushort* __restrict__ kb, ushort* __restrict__ vT) {
  __shared__ __align__(16) ushort sA[64 * 72];
  __shared__ __align__(16) ushort sB[192 * 72];
  int bid = blockIdx.x;
  int tid = threadIdx.x, lane = tid & 63, wid = tid >> 6;
  if (bid == 637) {
    for (int i = tid; i < 4096; i += 256) {
      int bh = i >> 8, rem = i & 255;
      int n = 784 + (rem >> 4), d = rem & 15;
      qb[((size_t)bh * 800 + n) * 16 + d] = 0;
      kb[((size_t)bh * 800 + n) * 16 + d] = 0;
      vT[((size_t)bh * 16 + d) * 800 + n] = 0;
    }
    return;
  }
  int lr = lane & 15, lk = (lane >> 4) * 8;
  if (bid < 588) {  // NAT LN1 + QKV
    int br = bid / 196, grp = bid % 196;
    const uint4* srcB = (const uint4*)(wT + br * 13824);
    for (int i = tid; i < 1728; i += 256) ((uint4*)sB)[i] = srcB[i];
    float g = nat_ln1_g[br * 64 + lane], bb = nat_ln1_b[br * 64 + lane];
#pragma unroll
    for (int i = 0; i < 16; ++i) {
      int pl = wid * 16 + i;
      float v = x[(size_t)(grp * 64 + pl) * 256 + br * 64 + lane];
      float s1 = wsum(v), s2 = wsum(v * v);
      float m = s1 * (1.f / 64.f);
      float var = s2 * (1.f / 64.f) - m * m;
      sA[pl * 72 + lane] = f2bf((v - m) * rsqrtf(var + 1e-5f) * g + bb);
    }
    __syncthreads();
    int m0 = wid * 16;
    bf16x8 a0 = *(const bf16x8*)&sA[(m0 + lr) * 72 + lk];
    bf16x8 a1 = *(const bf16x8*)&sA[(m0 + lr) * 72 + 32 + lk];
    int r0 = m0 + (lane >> 4) * 4;
#pragma unroll
    for (int nt = 0; nt < 12; ++nt) {
      int n0 = nt * 16;
      bf16x8 b0 = *(const bf16x8*)&sB[(n0 + lr) * 72 + lk];
      bf16x8 b1 = *(const bf16x8*)&sB[(n0 + lr) * 72 + 32 + lk];
      f32x4 acc = {0.f, 0.f, 0.f, 0.f};
      acc = __builtin_amdgcn_mfma_f32_16x16x32_bf16(a0, b0, acc, 0, 0, 0);
      acc = __builtin_amdgcn_mfma_f32_16x16x32_bf16(a1, b1, acc, 0, 0, 0);
      int col = n0 + lr;
      float bias = nat_qkv_b[br * 192 + col];
      if (nt < 4) {
        ushort* op = qn + ((size_t)br * NPIX + grp * 64 + r0) * 64 + col;
#pragma unroll
        for (int r = 0; r < 4; ++r) op[r * 64] = f2h((acc[r] + bias) * 0.25f);
      } else {
        ushort* op = kvn + ((size_t)br * NPIX + grp * 64 + r0) * 128 + (col - 64);
#pragma unroll
        for (int r = 0; r < 4; ++r) op[r * 128] = f2h(acc[r] + bias);
      }
    }
  } else {  // GA pool+LN + QKV via MFMA (49 blocks x 64 tokens)
    int g64 = bid - 588;
    const uint4* srcB = (const uint4*)(wT + 161280);
    for (int i = tid; i < 1728; i += 256) ((uint4*)sB)[i] = srcB[i];
    float gg = ga_ln1_g[lane], bb = ga_ln1_b[lane];
#pragma unroll
    for (int i = 0; i < 16; ++i) {
      int tl = wid * 16 + i;
      int token = g64 * 64 + tl;
      int b = token / 784, rem2 = token % 784, hp = rem2 / 28, wp = rem2 % 28;
      float s = 0.f;
#pragma unroll
      for (int dy = 0; dy < 2; ++dy)
#pragma unroll
        for (int dxx = 0; dxx < 2; ++dxx) {
          int pix = b * 3136 + (hp * 2 + dy) * 56 + (wp * 2 + dxx);
          float v = x[(size_t)pix * 256 + 192 + lane];
          float s1 = wsum(v), s2 = wsum(v * v);
          float m = s1 * (1.f / 64.f);
          float var = s2 * (1.f / 64.f) - m * m;
          s += (v - m) * rsqrtf(var + 1e-5f) * gg + bb;
        }
      sA[tl * 72 + lane] = f2bf(0.25f * s);
    }
    __syncthreads();
    int m0 = wid * 16;
    bf16x8 a0 = *(const bf16x8*)&sA[(m0 + lr) * 72 + lk];
    bf16x8 a1 = *(const bf16x8*)&sA[(m0 + lr) * 72 + 32 + lk];
    int r0 = m0 + (lane >> 4) * 4;
#pragma unroll
    for (int nt = 0; nt < 12; ++nt) {
      int n0 = nt * 16;
      bf16x8 b0 = *(const bf16x8*)&sB[(n0 + lr) * 72 + lk];
      bf16x8 b1 = *(const bf16x8*)&sB[(n0 + lr) * 72 + 32 + lk];
      f32x4 acc = {0.f, 0.f, 0.f, 0.f};
      acc = __builtin_amdgcn_mfma_f32_16x16x32_bf16(a0, b0, acc, 0, 0, 0);
      acc = __builtin_amdgcn_mfma_f32_16x16x32_bf16(a1, b1, acc, 0, 0, 0);
      int col = n0 + lr;
      float bias = ga_qkv_b[col];
      int hh = (col & 63) >> 4, d = col & 15;
#pragma unroll
      for (int r = 0; r < 4; ++r) {
        int token = g64 * 64 + r0 + r;
        int b = token / 784, nn = token % 784;
        float v = acc[r] + bias;
        if (col < 64)
          qb[((size_t)(b * 4 + hh) * 800 + nn) * 16 + d] = f2bf(v * 0.25f);
        else if (col < 128)
          kb[((size_t)(b * 4 + hh) * 800 + nn) * 16 + d] = f2bf(v);
        else
          vT[((size_t)(b * 4 + hh) * 16 + d) * 800 + nn] = f2bf(v);
      }
    }
  }
}

// ---------------- Kernel B: fused attention ----------------
// LDS union: phase 1 = 14x14 halo K/V (53,312 B); phase 2 = sAp(9,216)+sWp(9,216)
__global__ __launch_bounds__(256) void k_attn(
    const ushort* __restrict__ qn, const ushort* __restrict__ kvn,
    const float* __restrict__ rpb, const ushort* __restrict__ wT,
    const float* __restrict__ pb, const float* __restrict__ x,
    float* __restrict__ x1, const ushort* __restrict__ qb,
    const ushort* __restrict__ kb, const ushort* __restrict__ vT,
    float* __restrict__ x1g) {
  __shared__ __align__(16) ushort sBuf[196 * 136];  // 53,312 B -> 3 blocks/CU
  int bid = blockIdx.x;
  int tid = threadIdx.x, lane = tid & 63, wid = tid >> 6;
  if (bid < 588) {
    // NAT attention (f16 packed, b128 LDS reads) + proj + residual
    ushort* sKV = sBuf;
    int br = bid / 196, rem = bid % 196;
    int b = rem / 49, t = rem % 49;
    int y0 = (t / 7) * 8, x0 = (t % 7) * 8;
    int hy = min(max(y0 - 3, 0), 42), hx = min(max(x0 - 3, 0), 42);
    const ushort* kvbase = kvn + ((size_t)br * NPIX + b * 3136) * 128;
    for (int i = tid; i < 3136; i += 256) {
      int p = i >> 4, c = i & 15;
      int py = p / 14, px = p % 14;
      int gp = (hy + py) * 56 + (hx + px);
      uint4 v = *(const uint4*)&kvbase[(size_t)gp * 128 + c * 8];
      *(uint4*)&sKV[p * 136 + c * 8] = v;
    }
    __syncthreads();
    int pl = tid & 63, h = tid >> 6;
    int ly = pl >> 3, lx = pl & 7;
    int y = y0 + ly, xg = x0 + lx;
    int sy = min(max(y - 3, 0), 49), sx = min(max(xg - 3, 0), 49);
    int by = sy - hy, bx = sx - hx;
    int gpix = b * 3136 + y * 56 + xg;
    const ushort* qp = qn + ((size_t)br * NPIX + gpix) * 64 + h * 16;
    uint4 qv0 = *(const uint4*)&qp[0];
    uint4 qv1 = *(const uint4*)&qp[8];
    h2 q[8] = {bch2(qv0.x), bch2(qv0.y), bch2(qv0.z), bch2(qv0.w),
               bch2(qv1.x), bch2(qv1.y), bch2(qv1.z), bch2(qv1.w)};
    const float* rp = rpb + (br * 4 + h) * 169 + (sy - y + 6) * 13 + (sx - xg + 6);
    float m = -1e30f, l = 0.f;
    h2 acc[8];
    h2 z = {(_Float16)0.f, (_Float16)0.f};
#pragma unroll
    for (int i = 0; i < 8; ++i) acc[i] = z;
    for (int a = 0; a < 7; ++a) {
      const ushort* krow = &sKV[((by + a) * 14 + bx) * 136 + h * 16];
      for (int c = 0; c < 7; ++c) {
        const ushort* kp = krow + c * 136;
        uint4 k0 = *(const uint4*)&kp[0];   // ds_read_b128: stride-68dw, 8 hits/bank = free
        uint4 k1 = *(const uint4*)&kp[8];
        h2 d = z;
        d = bch2(k0.x) * q[0] + d;
        d = bch2(k0.y) * q[1] + d;
        d = bch2(k0.z) * q[2] + d;
        d = bch2(k0.w) * q[3] + d;
        d = bch2(k1.x) * q[4] + d;
        d = bch2(k1.y) * q[5] + d;
        d = bch2(k1.z) * q[6] + d;
        d = bch2(k1.w) * q[7] + d;
        float sd = (float)d[0] + (float)d[1] + rp[a * 13 + c];
        if (sd > m) {
          float sc = __expf(m - sd);
          m = sd; l *= sc;
          h2 sc2 = {(_Float16)sc, (_Float16)sc};
#pragma unroll
          for (int i = 0; i < 8; ++i) acc[i] = acc[i] * sc2;
        }
        float p = __expf(sd - m);
        l += p;
        h2 p2 = {(_Float16)p, (_Float16)p};
        uint4 v0 = *(const uint4*)&kp[64];
        uint4 v1 = *(const uint4*)&kp[72];
        acc[0] = bch2(v0.x) * p2 + acc[0];
        acc[1] = bch2(v0.y) * p2 + acc[1];
        acc[2] = bch2(v0.z) * p2 + acc[2];
        acc[3] = bch2(v0.w) * p2 + acc[3];
        acc[4] = bch2(v1.x) * p2 + acc[4];
        acc[5] = bch2(v1.y) * p2 + acc[5];
        acc[6] = bch2(v1.z) * p2 + acc[6];
        acc[7] = bch2(v1.w) * p2 + acc[7];
      }
    }
    float inv = 1.f / l;
    __syncthreads();  // everyone done reading sKV; repurpose as sAp/sWp
    ushort* sAp = sBuf;
    ushort* sWp = sBuf + 4608;
    const uint4* srcW = (const uint4*)(wT + 41472 + br * 4608);
    for (int i = tid; i < 576; i += 256) ((uint4*)sWp)[i] = srcW[i];
    uint32_t* ao = (uint32_t*)&sAp[pl * 72 + h * 16];
#pragma unroll
    for (int i = 0; i < 8; ++i)
      ao[i] = packbf((float)acc[i][0] * inv, (float)acc[i][1] * inv);
    __syncthreads();
    int lr = lane & 15, lk = (lane >> 4) * 8;
    int m0 = wid * 16;
    bf16x8 a0 = *(const bf16x8*)&sAp[(m0 + lr) * 72 + lk];
    bf16x8 a1 = *(const bf16x8*)&sAp[(m0 + lr) * 72 + 32 + lk];
    int r0 = m0 + (lane >> 4) * 4;
#pragma unroll
    for (int nt = 0; nt < 4; ++nt) {
      int n0 = nt * 16;
      bf16x8 b0 = *(const bf16x8*)&sWp[(n0 + lr) * 72 + lk];
      bf16x8 b1 = *(const bf16x8*)&sWp[(n0 + lr) * 72 + 32 + lk];
      f32x4 oacc = {0.f, 0.f, 0.f, 0.f};
      oacc = __builtin_amdgcn_mfma_f32_16x16x32_bf16(a0, b0, oacc, 0, 0, 0);
      oacc = __builtin_amdgcn_mfma_f32_16x16x32_bf16(a1, b1, oacc, 0, 0, 0);
      int col = n0 + lr;
      float bias = pb[br * 64 + col];
#pragma unroll
      for (int r = 0; r < 4; ++r) {
        int rr = r0 + r;
        int gp2 = b * 3136 + (y0 + (rr >> 3)) * 56 + (x0 + (rr & 7));
        x1[((size_t)br * NPIX + gp2) * 64 + col] =
            oacc[r] + bias + x[(size_t)gp2 * 256 + br * 64 + col];
      }
    }
  } else {
    // GA attention: wave = q-tile
    int wt = (bid - 588) * 4 + wid;
    int bh = wt / 25, qt = wt % 25;
    int h = bh & 3, b = bh >> 2;
    int qrow = lane & 31, hi = lane >> 5;
    int dmod = lane & 15;
    const ushort* qbase = qb + (size_t)bh * 800 * 16;
    const ushort* kbase = kb + (size_t)bh * 800 * 16;
    const ushort* vbase = vT + (size_t)bh * 16 * 800 + (size_t)dmod * 800;
    bf16x8 qf = *(const bf16x8*)&qbase[(qt * 32 + qrow) * 16 + hi * 8];
    float m = -1e30f, l = 0.f;
    f32x16 acc_o;
#pragma unroll
    for (int r = 0; r < 16; ++r) acc_o[r] = 0.f;
    bf16x8 kf = *(const bf16x8*)&kbase[(0 + qrow) * 16 + hi * 8];
    bf16x8 vf0 = *(const bf16x8*)&vbase[0 + hi * 8];
    bf16x8 vf1 = *(const bf16x8*)&vbase[16 + hi * 8];
    for (int kt = 0; kt < 25; ++kt) {
      int nb = (kt < 24 ? kt + 1 : 24) * 32;
      bf16x8 nkf = *(const bf16x8*)&kbase[(nb + qrow) * 16 + hi * 8];
      bf16x8 nvf0 = *(const bf16x8*)&vbase[nb + hi * 8];
      bf16x8 nvf1 = *(const bf16x8*)&vbase[nb + 16 + hi * 8];
      f32x16 zero;
#pragma unroll
      for (int r = 0; r < 16; ++r) zero[r] = 0.f;
      f32x16 st = __builtin_amdgcn_mfma_f32_32x32x16_bf16(kf, qf, zero, 0, 0, 0);
      float s[16];
#pragma unroll
      for (int r = 0; r < 16; ++r) s[r] = st[r];
      if (kt == 24) {
#pragma unroll
        for (int r = 8; r < 16; ++r) s[r] = -1e30f;
      }
      float tm = s[0];
#pragma unroll
      for (int r = 1; r < 16; ++r) tm = fmaxf(tm, s[r]);
      tm = fmaxf(tm, __shfl_xor(tm, 32, 64));
      if (__any(tm > m + 8.f)) {
        float mn = fmaxf(m, tm);
        float sc = __expf(m - mn);
        l *= sc;
        m = mn;
#pragma unroll
        for (int r = 0; r < 16; ++r) {
          int row = (r & 3) + 4 * hi + 8 * (r >> 2);
          float scr = __shfl(sc, row, 64);
          acc_o[r] *= scr;
        }
      }
      uint32_t pk[8];
      float ps = 0.f;
#pragma unroll
      for (int i = 0; i < 8; ++i) {
        float p0 = __expf(s[2 * i] - m), p1 = __expf(s[2 * i + 1] - m);
        ps += p0 + p1;
        pk[i] = packbf(p0, p1);
      }
      l += ps;
#pragma unroll
      for (int t = 0; t < 2; ++t) {
        uint32_t c0 = pk[4 * t + 0], c1 = pk[4 * t + 1];
        uint32_t c2 = pk[4 * t + 2], c3 = pk[4 * t + 3];
        uint32_t b00 = __shfl((int)c0, qrow, 64), b02 = __shfl((int)c2, qrow, 64);
        uint32_t b10 = __shfl((int)c1, qrow, 64), b12 = __shfl((int)c3, qrow, 64);
        uint32_t b20 = __shfl((int)c0, qrow + 32, 64), b22 = __shfl((int)c2, qrow + 32, 64);
        uint32_t b30 = __shfl((int)c1, qrow + 32, 64), b32 = __shfl((int)c3, qrow + 32, 64);
        union { uint32_t u[4]; bf16x8 v; } pa;
        pa.u[0] = hi ? b02 : b00;
        pa.u[1] = hi ? b12 : b10;
        pa.u[2] = hi ? b22 : b20;
        pa.u[3] = hi ? b32 : b30;
        acc_o = __builtin_amdgcn_mfma_f32_32x32x16_bf16(pa.v, (t ? vf1 : vf0),
                                                        acc_o, 0, 0, 0);
      }
      kf = nkf; vf0 = nvf0; vf1 = nvf1;
    }
    l += __shfl_xor(l, 32, 64);
    float inv = 1.f / l;
#pragma unroll
    for (int r = 0; r < 16; ++r) {
      int row = (r & 3) + 4 * hi + 8 * (r >> 2);
      float invr = __shfl(inv, row, 64);
      int n = qt * 32 + row;
      if (n < 784 && qrow < 16) {
        float o = acc_o[r] * invr;
        int hp = n / 28, wp = n % 28;
        int ch = h * 16 + dmod;
#pragma unroll
        for (int dy = 0; dy < 2; ++dy)
#pragma unroll
          for (int dxx = 0; dxx < 2; ++dxx) {
            int pix = b * 3136 + (hp * 2 + dy) * 56 + (wp * 2 + dxx);
            x1g[(size_t)pix * 64 + ch] = x[(size_t)pix * 256 + 192 + ch] + o;
          }
      }
    }
  }
}

// ---------------- Kernel C: fused MLP ----------------
template <bool NAT>
__device__ __forceinline__ void mlp_body(
    int br, int grp, ushort* sX, ushort* sH, ushort* sW,
    const float* __restrict__ x1, const ushort* __restrict__ W1,
    const ushort* __restrict__ W2, const float* __restrict__ B1,
    const float* __restrict__ B2, const float* __restrict__ G,
    const float* __restrict__ Bt, float* __restrict__ out) {
  constexpr int H1 = NAT ? 256 : 192;
  constexpr int K2P = NAT ? 264 : 200;
  constexpr int KB = H1 / 32;
  int tid = threadIdx.x, lane = tid & 63, wid = tid >> 6;
  const float* xin = x1 + ((size_t)br * NPIX + grp * 64) * 64;
  constexpr int NW1 = H1 * 9;
  for (int i = tid; i < NW1; i += 256) ((uint4*)sW)[i] = ((const uint4*)W1)[i];
  float g = G[lane], bb = Bt[lane];
#pragma unroll
  for (int i = 0; i < 16; ++i) {
    int pl = wid * 16 + i;
    float v = xin[pl * 64 + lane];
    float s1 = wsum(v), s2 = wsum(v * v);
    float m = s1 * (1.f / 64.f);
    float var = s2 * (1.f / 64.f) - m * m;
    sX[pl * 72 + lane] = f2bf((v - m) * rsqrtf(var + 1e-5f) * g + bb);
  }
  __syncthreads();
  int lr = lane & 15, lk = (lane >> 4) * 8;
  int mbase = (wid & 1) * 16;
  int r0 = (lane >> 4) * 4;
  bf16x8 a0[2], a1[2];
#pragma unroll
  for (int mh = 0; mh < 2; ++mh) {
    int m0 = mh * 32 + mbase;
    a0[mh] = *(const bf16x8*)&sX[(m0 + lr) * 72 + lk];
    a1[mh] = *(const bf16x8*)&sX[(m0 + lr) * 72 + 32 + lk];
  }
#pragma unroll
  for (int t2 = 0; t2 < H1 / 32; ++t2) {
    int n0 = ((wid >> 1) + 2 * t2) * 16;
    bf16x8 b0 = *(const bf16x8*)&sW[(n0 + lr) * 72 + lk];
    bf16x8 b1 = *(const bf16x8*)&sW[(n0 + lr) * 72 + 32 + lk];
    int col = n0 + lr;
    float b1v = B1[col];
#pragma unroll
    for (int mh = 0; mh < 2; ++mh) {
      f32x4 acc = {0.f, 0.f, 0.f, 0.f};
      acc = __builtin_amdgcn_mfma_f32_16x16x32_bf16(a0[mh], b0, acc, 0, 0, 0);
      acc = __builtin_amdgcn_mfma_f32_16x16x32_bf16(a1[mh], b1, acc, 0, 0, 0);
      int m0 = mh * 32 + mbase;
#pragma unroll
      for (int r = 0; r < 4; ++r)
        sH[(m0 + r0 + r) * K2P + col] = f2bf(gelu_fast(acc[r] + b1v));
    }
  }
  __syncthreads();
  constexpr int NW2 = 64 * K2P / 8;
  for (int i = tid; i < NW2; i += 256) ((uint4*)sW)[i] = ((const uint4*)W2)[i];
  __syncthreads();
#pragma unroll
  for (int mh = 0; mh < 2; ++mh) {
    int m0 = mh * 32 + mbase;
    bf16x8 af[KB];
#pragma unroll
    for (int kb = 0; kb < KB; ++kb)
      af[kb] = *(const bf16x8*)&sH[(m0 + lr) * K2P + kb * 32 + lk];
#pragma unroll
    for (int u = 0; u < 2; ++u) {
      int n0 = ((wid >> 1) + 2 * u) * 16;
      f32x4 acc = {0.f, 0.f, 0.f, 0.f};
#pragma unroll
      for (int kb = 0; kb < KB; ++kb) {
        bf16x8 bf = *(const bf16x8*)&sW[(n0 + lr) * K2P + kb * 32 + lk];
        acc = __builtin_amdgcn_mfma_f32_16x16x32_bf16(af[kb], bf, acc, 0, 0, 0);
      }
      int col = n0 + lr;
      float b2v = B2[col];
#pragma unroll
      for (int r = 0; r < 4; ++r) {
        int p = m0 + r0 + r;
        int pix = grp * 64 + p;
        out[(size_t)pix * 256 + br * 64 + col] = xin[p * 64 + col] + acc[r] + b2v;
      }
    }
  }
}

__global__ __launch_bounds__(256) void k_mlp(
    const float* __restrict__ x1, const float* __restrict__ nat_ln2_g,
    const float* __restrict__ nat_ln2_b, const ushort* __restrict__ wT,
    const float* __restrict__ nat_f1b, const float* __restrict__ nat_f2b,
    const float* __restrict__ ga_ln2_g, const float* __restrict__ ga_ln2_b,
    const float* __restrict__ ga_f1b, const float* __restrict__ ga_f2b,
    float* __restrict__ out) {
  __shared__ __align__(16) ushort sX[64 * 72];
  __shared__ __align__(16) ushort sH[64 * 264];
  __shared__ __align__(16) ushort sW[256 * 72];
  int bid = blockIdx.x;
  if (bid < 588) {
    int br = bid / 196, grp = bid % 196;
    mlp_body<true>(br, grp, sX, sH, sW, x1, wT + 55296 + br * 18432,
                   wT + 110592 + br * 16896, nat_f1b + br * 256,
                   nat_f2b + br * 64, nat_ln2_g + br * 64, nat_ln2_b + br * 64,
                   out);
  } else {
    int grp = bid - 588;
    mlp_body<false>(3, grp, sX, sH, sW, x1, wT + 175104, wT + 188928, ga_f1b,
                    ga_f2b, ga_ln2_g, ga_ln2_b, out);
  }
}

}  // namespace

extern "C" void kernel_launch(void* const* d_in, const int* in_sizes, int n_in,
                              void* d_out, int out_size, void* d_ws, size_t ws_size,
                              hipStream_t stream) {
  const float* x = (const float*)d_in[0];
  const float* nat_ln1_g = (const float*)d_in[1];
  const float* nat_ln1_b = (const float*)d_in[2];
  const float* nat_qkv_w = (const float*)d_in[3];
  const float* nat_qkv_b = (const float*)d_in[4];
  const float* nat_rpb = (const float*)d_in[5];
  const float* nat_proj_w = (const float*)d_in[6];
  const float* nat_proj_b = (const float*)d_in[7];
  const float* nat_ln2_g = (const float*)d_in[8];
  const float* nat_ln2_b = (const float*)d_in[9];
  const float* nat_fc1_w = (const float*)d_in[10];
  const float* nat_fc1_b = (const float*)d_in[11];
  const float* nat_fc2_w = (const float*)d_in[12];
  const float* nat_fc2_b = (const float*)d_in[13];
  const float* ga_ln1_g = (const float*)d_in[14];
  const float* ga_ln1_b = (const float*)d_in[15];
  const float* ga_qkv_w = (const float*)d_in[16];
  const float* ga_qkv_b = (const float*)d_in[17];
  const float* ga_ln2_g = (const float*)d_in[18];
  const float* ga_ln2_b = (const float*)d_in[19];
  const float* ga_fc1_w = (const float*)d_in[20];
  const float* ga_fc1_b = (const float*)d_in[21];
  const float* ga_fc2_w = (const float*)d_in[22];
  const float* ga_fc2_b = (const float*)d_in[23];

  uint8_t* w8 = (uint8_t*)d_ws;
  ushort* qn  = (ushort*)w8;                  //  4,816,896 B (f16)
  ushort* kvn = (ushort*)(w8 + 4816896);      //  9,633,792 B (f16)
  float*  x1  = (float*)(w8 + 14450688);      // 12,845,056 B
  ushort* wT  = (ushort*)(w8 + 27295744);     //    403,456 B
  ushort* qgb = (ushort*)(w8 + 27699200);     //    409,600 B
  ushort* kgb = (ushort*)(w8 + 28108800);     //    409,600 B
  ushort* vgT = (ushort*)(w8 + 28518400);     //    409,600 B
  // total ~28.9 MB

  k_prep<<<dim3(789), dim3(256), 0, stream>>>(nat_qkv_w, nat_proj_w, nat_fc1_w,
                                              nat_fc2_w, ga_qkv_w, ga_fc1_w,
                                              ga_fc2_w, wT);
  k_qkv<<<dim3(638), dim3(256), 0, stream>>>(x, nat_ln1_g, nat_ln1_b, wT,
                                             nat_qkv_b, qn, kvn, ga_ln1_g,
                                             ga_ln1_b, ga_qkv_b, qgb, kgb, vgT);
  k_attn<<<dim3(688), dim3(256), 0, stream>>>(qn, kvn, nat_rpb, wT, nat_proj_b,
                                              x, x1, qgb, kgb, vgT,
                                              x1 + (size_t)3 * NPIX * 64);
  k_mlp<<<dim3(784), dim3(256), 0, stream>>>(x1, nat_ln2_g, nat_ln2_b, wT,
                                             nat_fc1_b, nat_fc2_b, ga_ln2_g,
                                             ga_ln2_b, ga_fc1_b, ga_fc2_b,
                                             (float*)d_out);
}

// Round 10
// 85.203 us; speedup vs baseline: 1.6005x; 1.0634x over previous
//
#include <hip/hip_runtime.h>
#include <hip/hip_bf16.h>
#include <cstdint>

namespace {

constexpr int NPIX = 12544;   // 4*56*56

typedef __attribute__((ext_vector_type(8))) short bf16x8;
typedef __attribute__((ext_vector_type(4))) float f32x4;
typedef __attribute__((ext_vector_type(16))) float f32x16;
typedef _Float16 h2 __attribute__((ext_vector_type(2)));

__device__ __forceinline__ float wsum(float v) {
#pragma unroll
  for (int m = 32; m; m >>= 1) v += __shfl_xor(v, m, 64);
  return v;
}

__device__ __forceinline__ uint16_t f2bf(float f) {
  uint32_t u = __builtin_bit_cast(uint32_t, f);
  u += 0x7fffu + ((u >> 16) & 1u);
  return (uint16_t)(u >> 16);
}
__device__ __forceinline__ uint32_t packbf(float a, float b) {
  return (uint32_t)f2bf(a) | ((uint32_t)f2bf(b) << 16);
}
__device__ __forceinline__ ushort f2h(float f) {
  _Float16 h = (_Float16)f;
  return __builtin_bit_cast(ushort, h);
}
__device__ __forceinline__ h2 bch2(uint32_t u) { return __builtin_bit_cast(h2, u); }

__device__ __forceinline__ float gelu_fast(float v) {
  float u = 0.7978845608028654f * (v + 0.044715f * v * v * v);
  float e = __expf(2.f * u);
  float th = 1.f - 2.f * __builtin_amdgcn_rcpf(e + 1.f);
  return 0.5f * v * (1.f + th);
}

// ---------------- Prep: convert+transpose all weights to bf16 ----------------
__global__ __launch_bounds__(256) void k_prep(
    const float* __restrict__ nqkv, const float* __restrict__ nproj,
    const float* __restrict__ nf1, const float* __restrict__ nf2,
    const float* __restrict__ gqkv, const float* __restrict__ gf1,
    const float* __restrict__ gf2, ushort* __restrict__ wT) {
  int t = blockIdx.x * 256 + threadIdx.x;
  if (t >= 201728) return;
  int i = t;
  if (i < 41472) {
    int br = i / 13824, r = i % 13824, n = r / 72, k = r % 72;
    wT[t] = k < 64 ? f2bf(nqkv[(br * 64 + k) * 192 + n]) : (ushort)0;
    return;
  }
  i -= 41472;
  if (i < 13824) {
    int br = i / 4608, r = i % 4608, n = r / 72, k = r % 72;
    wT[t] = k < 64 ? f2bf(nproj[(br * 64 + k) * 64 + n]) : (ushort)0;
    return;
  }
  i -= 13824;
  if (i < 55296) {
    int br = i / 18432, r = i % 18432, n = r / 72, k = r % 72;
    wT[t] = k < 64 ? f2bf(nf1[(br * 64 + k) * 256 + n]) : (ushort)0;
    return;
  }
  i -= 55296;
  if (i < 50688) {
    int br = i / 16896, r = i % 16896, n = r / 264, k = r % 264;
    wT[t] = k < 256 ? f2bf(nf2[(br * 256 + k) * 64 + n]) : (ushort)0;
    return;
  }
  i -= 50688;
  if (i < 13824) {
    int n = i / 72, k = i % 72;
    wT[t] = k < 64 ? f2bf(gqkv[k * 192 + n]) : (ushort)0;
    return;
  }
  i -= 13824;
  if (i < 13824) {
    int n = i / 72, k = i % 72;
    wT[t] = k < 64 ? f2bf(gf1[k * 192 + n]) : (ushort)0;
    return;
  }
  i -= 13824;
  {
    int n = i / 200, k = i % 200;
    wT[t] = k < 192 ? f2bf(gf2[k * 64 + n]) : (ushort)0;
  }
}

// ---------------- Kernel A: fused QKV — NAT (0..587) | GA (588..636) | pad (637)
// weights read directly from global wT (L2-resident) as MFMA B-fragments
__global__ __launch_bounds__(256) void k_qkv(
    const float* __restrict__ x, const float* __restrict__ nat_ln1_g,
    const float* __restrict__ nat_ln1_b, const ushort* __restrict__ wT,
    const float* __restrict__ nat_qkv_b, ushort* __restrict__ qn,
    ushort* __restrict__ kvn, const float* __restrict__ ga_ln1_g,
    const float* __restrict__ ga_ln1_b, const float* __restrict__ ga_qkv_b,
    ushort* __restrict__ qb, ushort* __restrict__ kb, ushort* __restrict__ vT) {
  __shared__ __align__(16) ushort sA[64 * 72];
  int bid = blockIdx.x;
  int tid = threadIdx.x, lane = tid & 63, wid = tid >> 6;
  if (bid == 637) {
    for (int i = tid; i < 4096; i += 256) {
      int bh = i >> 8, rem = i & 255;
      int n = 784 + (rem >> 4), d = rem & 15;
      qb[((size_t)bh * 800 + n) * 16 + d] = 0;
      kb[((size_t)bh * 800 + n) * 16 + d] = 0;
      vT[((size_t)bh * 16 + d) * 800 + n] = 0;
    }
    return;
  }
  int lr = lane & 15, lk = (lane >> 4) * 8;
  if (bid < 588) {  // NAT LN1 + QKV
    int br = bid / 196, grp = bid % 196;
    const ushort* Wg = wT + br * 13824;
    float g = nat_ln1_g[br * 64 + lane], bb = nat_ln1_b[br * 64 + lane];
#pragma unroll
    for (int i = 0; i < 16; ++i) {
      int pl = wid * 16 + i;
      float v = x[(size_t)(grp * 64 + pl) * 256 + br * 64 + lane];
      float s1 = wsum(v), s2 = wsum(v * v);
      float m = s1 * (1.f / 64.f);
      float var = s2 * (1.f / 64.f) - m * m;
      sA[pl * 72 + lane] = f2bf((v - m) * rsqrtf(var + 1e-5f) * g + bb);
    }
    __syncthreads();
    int m0 = wid * 16;
    bf16x8 a0 = *(const bf16x8*)&sA[(m0 + lr) * 72 + lk];
    bf16x8 a1 = *(const bf16x8*)&sA[(m0 + lr) * 72 + 32 + lk];
    int r0 = m0 + (lane >> 4) * 4;
#pragma unroll
    for (int nt = 0; nt < 12; ++nt) {
      int n0 = nt * 16;
      bf16x8 b0 = *(const bf16x8*)&Wg[(n0 + lr) * 72 + lk];
      bf16x8 b1 = *(const bf16x8*)&Wg[(n0 + lr) * 72 + 32 + lk];
      f32x4 acc = {0.f, 0.f, 0.f, 0.f};
      acc = __builtin_amdgcn_mfma_f32_16x16x32_bf16(a0, b0, acc, 0, 0, 0);
      acc = __builtin_amdgcn_mfma_f32_16x16x32_bf16(a1, b1, acc, 0, 0, 0);
      int col = n0 + lr;
      float bias = nat_qkv_b[br * 192 + col];
      if (nt < 4) {
        ushort* op = qn + ((size_t)br * NPIX + grp * 64 + r0) * 64 + col;
#pragma unroll
        for (int r = 0; r < 4; ++r) op[r * 64] = f2h((acc[r] + bias) * 0.25f);
      } else {
        ushort* op = kvn + ((size_t)br * NPIX + grp * 64 + r0) * 128 + (col - 64);
#pragma unroll
        for (int r = 0; r < 4; ++r) op[r * 128] = f2h(acc[r] + bias);
      }
    }
  } else {  // GA pool+LN + QKV via MFMA (49 blocks x 64 tokens)
    int g64 = bid - 588;
    const ushort* Wg = wT + 161280;
    float gg = ga_ln1_g[lane], bb = ga_ln1_b[lane];
#pragma unroll
    for (int i = 0; i < 16; ++i) {
      int tl = wid * 16 + i;
      int token = g64 * 64 + tl;
      int b = token / 784, rem2 = token % 784, hp = rem2 / 28, wp = rem2 % 28;
      float s = 0.f;
#pragma unroll
      for (int dy = 0; dy < 2; ++dy)
#pragma unroll
        for (int dxx = 0; dxx < 2; ++dxx) {
          int pix = b * 3136 + (hp * 2 + dy) * 56 + (wp * 2 + dxx);
          float v = x[(size_t)pix * 256 + 192 + lane];
          float s1 = wsum(v), s2 = wsum(v * v);
          float m = s1 * (1.f / 64.f);
          float var = s2 * (1.f / 64.f) - m * m;
          s += (v - m) * rsqrtf(var + 1e-5f) * gg + bb;
        }
      sA[tl * 72 + lane] = f2bf(0.25f * s);
    }
    __syncthreads();
    int m0 = wid * 16;
    bf16x8 a0 = *(const bf16x8*)&sA[(m0 + lr) * 72 + lk];
    bf16x8 a1 = *(const bf16x8*)&sA[(m0 + lr) * 72 + 32 + lk];
    int r0 = m0 + (lane >> 4) * 4;
#pragma unroll
    for (int nt = 0; nt < 12; ++nt) {
      int n0 = nt * 16;
      bf16x8 b0 = *(const bf16x8*)&Wg[(n0 + lr) * 72 + lk];
      bf16x8 b1 = *(const bf16x8*)&Wg[(n0 + lr) * 72 + 32 + lk];
      f32x4 acc = {0.f, 0.f, 0.f, 0.f};
      acc = __builtin_amdgcn_mfma_f32_16x16x32_bf16(a0, b0, acc, 0, 0, 0);
      acc = __builtin_amdgcn_mfma_f32_16x16x32_bf16(a1, b1, acc, 0, 0, 0);
      int col = n0 + lr;
      float bias = ga_qkv_b[col];
      int hh = (col & 63) >> 4, d = col & 15;
#pragma unroll
      for (int r = 0; r < 4; ++r) {
        int token = g64 * 64 + r0 + r;
        int b = token / 784, nn = token % 784;
        float v = acc[r] + bias;
        if (col < 64)
          qb[((size_t)(b * 4 + hh) * 800 + nn) * 16 + d] = f2bf(v * 0.25f);
        else if (col < 128)
          kb[((size_t)(b * 4 + hh) * 800 + nn) * 16 + d] = f2bf(v);
        else
          vT[((size_t)(b * 4 + hh) * 16 + d) * 800 + nn] = f2bf(v);
      }
    }
  }
}

// ---------------- Kernel B: fused attention ----------------
// LDS union: phase 1 = 14x14 halo K/V (53,312 B); phase 2 = sAp (9,216 B)
__global__ __launch_bounds__(256) void k_attn(
    const ushort* __restrict__ qn, const ushort* __restrict__ kvn,
    const float* __restrict__ rpb, const ushort* __restrict__ wT,
    const float* __restrict__ pb, const float* __restrict__ x,
    float* __restrict__ x1, const ushort* __restrict__ qb,
    const ushort* __restrict__ kb, const ushort* __restrict__ vT,
    float* __restrict__ x1g) {
  __shared__ __align__(16) ushort sBuf[196 * 136];  // 53,312 B -> 3 blocks/CU
  int bid = blockIdx.x;
  int tid = threadIdx.x, lane = tid & 63, wid = tid >> 6;
  if (bid < 588) {
    // NAT attention (f16 packed, b128 LDS reads) + proj + residual
    ushort* sKV = sBuf;
    int br = bid / 196, rem = bid % 196;
    int b = rem / 49, t = rem % 49;
    int y0 = (t / 7) * 8, x0 = (t % 7) * 8;
    int hy = min(max(y0 - 3, 0), 42), hx = min(max(x0 - 3, 0), 42);
    const ushort* kvbase = kvn + ((size_t)br * NPIX + b * 3136) * 128;
    for (int i = tid; i < 3136; i += 256) {
      int p = i >> 4, c = i & 15;
      int py = p / 14, px = p % 14;
      int gp = (hy + py) * 56 + (hx + px);
      uint4 v = *(const uint4*)&kvbase[(size_t)gp * 128 + c * 8];
      *(uint4*)&sKV[p * 136 + c * 8] = v;
    }
    __syncthreads();
    int pl = tid & 63, h = tid >> 6;
    int ly = pl >> 3, lx = pl & 7;
    int y = y0 + ly, xg = x0 + lx;
    int sy = min(max(y - 3, 0), 49), sx = min(max(xg - 3, 0), 49);
    int by = sy - hy, bx = sx - hx;
    int gpix = b * 3136 + y * 56 + xg;
    const ushort* qp = qn + ((size_t)br * NPIX + gpix) * 64 + h * 16;
    uint4 qv0 = *(const uint4*)&qp[0];
    uint4 qv1 = *(const uint4*)&qp[8];
    h2 q[8] = {bch2(qv0.x), bch2(qv0.y), bch2(qv0.z), bch2(qv0.w),
               bch2(qv1.x), bch2(qv1.y), bch2(qv1.z), bch2(qv1.w)};
    const float* rp = rpb + (br * 4 + h) * 169 + (sy - y + 6) * 13 + (sx - xg + 6);
    float m = -1e30f, l = 0.f;
    h2 acc[8];
    h2 z = {(_Float16)0.f, (_Float16)0.f};
#pragma unroll
    for (int i = 0; i < 8; ++i) acc[i] = z;
    for (int a = 0; a < 7; ++a) {
      const ushort* krow = &sKV[((by + a) * 14 + bx) * 136 + h * 16];
      for (int c = 0; c < 7; ++c) {
        const ushort* kp = krow + c * 136;
        uint4 k0 = *(const uint4*)&kp[0];
        uint4 k1 = *(const uint4*)&kp[8];
        h2 d = z;
        d = bch2(k0.x) * q[0] + d;
        d = bch2(k0.y) * q[1] + d;
        d = bch2(k0.z) * q[2] + d;
        d = bch2(k0.w) * q[3] + d;
        d = bch2(k1.x) * q[4] + d;
        d = bch2(k1.y) * q[5] + d;
        d = bch2(k1.z) * q[6] + d;
        d = bch2(k1.w) * q[7] + d;
        float sd = (float)d[0] + (float)d[1] + rp[a * 13 + c];
        if (sd > m) {
          float sc = __expf(m - sd);
          m = sd; l *= sc;
          h2 sc2 = {(_Float16)sc, (_Float16)sc};
#pragma unroll
          for (int i = 0; i < 8; ++i) acc[i] = acc[i] * sc2;
        }
        float p = __expf(sd - m);
        l += p;
        h2 p2 = {(_Float16)p, (_Float16)p};
        uint4 v0 = *(const uint4*)&kp[64];
        uint4 v1 = *(const uint4*)&kp[72];
        acc[0] = bch2(v0.x) * p2 + acc[0];
        acc[1] = bch2(v0.y) * p2 + acc[1];
        acc[2] = bch2(v0.z) * p2 + acc[2];
        acc[3] = bch2(v0.w) * p2 + acc[3];
        acc[4] = bch2(v1.x) * p2 + acc[4];
        acc[5] = bch2(v1.y) * p2 + acc[5];
        acc[6] = bch2(v1.z) * p2 + acc[6];
        acc[7] = bch2(v1.w) * p2 + acc[7];
      }
    }
    float inv = 1.f / l;
    __syncthreads();  // everyone done reading sKV; repurpose as sAp
    ushort* sAp = sBuf;
    uint32_t* ao = (uint32_t*)&sAp[pl * 72 + h * 16];
#pragma unroll
    for (int i = 0; i < 8; ++i)
      ao[i] = packbf((float)acc[i][0] * inv, (float)acc[i][1] * inv);
    __syncthreads();
    const ushort* Wp = wT + 41472 + br * 4608;
    int lr = lane & 15, lk = (lane >> 4) * 8;
    int m0 = wid * 16;
    bf16x8 a0 = *(const bf16x8*)&sAp[(m0 + lr) * 72 + lk];
    bf16x8 a1 = *(const bf16x8*)&sAp[(m0 + lr) * 72 + 32 + lk];
    int r0 = m0 + (lane >> 4) * 4;
#pragma unroll
    for (int nt = 0; nt < 4; ++nt) {
      int n0 = nt * 16;
      bf16x8 b0 = *(const bf16x8*)&Wp[(n0 + lr) * 72 + lk];
      bf16x8 b1 = *(const bf16x8*)&Wp[(n0 + lr) * 72 + 32 + lk];
      f32x4 oacc = {0.f, 0.f, 0.f, 0.f};
      oacc = __builtin_amdgcn_mfma_f32_16x16x32_bf16(a0, b0, oacc, 0, 0, 0);
      oacc = __builtin_amdgcn_mfma_f32_16x16x32_bf16(a1, b1, oacc, 0, 0, 0);
      int col = n0 + lr;
      float bias = pb[br * 64 + col];
#pragma unroll
      for (int r = 0; r < 4; ++r) {
        int rr = r0 + r;
        int gp2 = b * 3136 + (y0 + (rr >> 3)) * 56 + (x0 + (rr & 7));
        x1[((size_t)br * NPIX + gp2) * 64 + col] =
            oacc[r] + bias + x[(size_t)gp2 * 256 + br * 64 + col];
      }
    }
  } else {
    // GA attention: wave = q-tile
    int wt = (bid - 588) * 4 + wid;
    int bh = wt / 25, qt = wt % 25;
    int h = bh & 3, b = bh >> 2;
    int qrow = lane & 31, hi = lane >> 5;
    int dmod = lane & 15;
    const ushort* qbase = qb + (size_t)bh * 800 * 16;
    const ushort* kbase = kb + (size_t)bh * 800 * 16;
    const ushort* vbase = vT + (size_t)bh * 16 * 800 + (size_t)dmod * 800;
    bf16x8 qf = *(const bf16x8*)&qbase[(qt * 32 + qrow) * 16 + hi * 8];
    float m = -1e30f, l = 0.f;
    f32x16 acc_o;
#pragma unroll
    for (int r = 0; r < 16; ++r) acc_o[r] = 0.f;
    bf16x8 kf = *(const bf16x8*)&kbase[(0 + qrow) * 16 + hi * 8];
    bf16x8 vf0 = *(const bf16x8*)&vbase[0 + hi * 8];
    bf16x8 vf1 = *(const bf16x8*)&vbase[16 + hi * 8];
    for (int kt = 0; kt < 25; ++kt) {
      int nb = (kt < 24 ? kt + 1 : 24) * 32;
      bf16x8 nkf = *(const bf16x8*)&kbase[(nb + qrow) * 16 + hi * 8];
      bf16x8 nvf0 = *(const bf16x8*)&vbase[nb + hi * 8];
      bf16x8 nvf1 = *(const bf16x8*)&vbase[nb + 16 + hi * 8];
      f32x16 zero;
#pragma unroll
      for (int r = 0; r < 16; ++r) zero[r] = 0.f;
      f32x16 st = __builtin_amdgcn_mfma_f32_32x32x16_bf16(kf, qf, zero, 0, 0, 0);
      float s[16];
#pragma unroll
      for (int r = 0; r < 16; ++r) s[r] = st[r];
      if (kt == 24) {
#pragma unroll
        for (int r = 8; r < 16; ++r) s[r] = -1e30f;
      }
      float tm = s[0];
#pragma unroll
      for (int r = 1; r < 16; ++r) tm = fmaxf(tm, s[r]);
      tm = fmaxf(tm, __shfl_xor(tm, 32, 64));
      if (__any(tm > m + 8.f)) {
        float mn = fmaxf(m, tm);
        float sc = __expf(m - mn);
        l *= sc;
        m = mn;
#pragma unroll
        for (int r = 0; r < 16; ++r) {
          int row = (r & 3) + 4 * hi + 8 * (r >> 2);
          float scr = __shfl(sc, row, 64);
          acc_o[r] *= scr;
        }
      }
      uint32_t pk[8];
      float ps = 0.f;
#pragma unroll
      for (int i = 0; i < 8; ++i) {
        float p0 = __expf(s[2 * i] - m), p1 = __expf(s[2 * i + 1] - m);
        ps += p0 + p1;
        pk[i] = packbf(p0, p1);
      }
      l += ps;
#pragma unroll
      for (int t = 0; t < 2; ++t) {
        uint32_t c0 = pk[4 * t + 0], c1 = pk[4 * t + 1];
        uint32_t c2 = pk[4 * t + 2], c3 = pk[4 * t + 3];
        uint32_t b00 = __shfl((int)c0, qrow, 64), b02 = __shfl((int)c2, qrow, 64);
        uint32_t b10 = __shfl((int)c1, qrow, 64), b12 = __shfl((int)c3, qrow, 64);
        uint32_t b20 = __shfl((int)c0, qrow + 32, 64), b22 = __shfl((int)c2, qrow + 32, 64);
        uint32_t b30 = __shfl((int)c1, qrow + 32, 64), b32 = __shfl((int)c3, qrow + 32, 64);
        union { uint32_t u[4]; bf16x8 v; } pa;
        pa.u[0] = hi ? b02 : b00;
        pa.u[1] = hi ? b12 : b10;
        pa.u[2] = hi ? b22 : b20;
        pa.u[3] = hi ? b32 : b30;
        acc_o = __builtin_amdgcn_mfma_f32_32x32x16_bf16(pa.v, (t ? vf1 : vf0),
                                                        acc_o, 0, 0, 0);
      }
      kf = nkf; vf0 = nvf0; vf1 = nvf1;
    }
    l += __shfl_xor(l, 32, 64);
    float inv = 1.f / l;
#pragma unroll
    for (int r = 0; r < 16; ++r) {
      int row = (r & 3) + 4 * hi + 8 * (r >> 2);
      float invr = __shfl(inv, row, 64);
      int n = qt * 32 + row;
      if (n < 784 && qrow < 16) {
        float o = acc_o[r] * invr;
        int hp = n / 28, wp = n % 28;
        int ch = h * 16 + dmod;
#pragma unroll
        for (int dy = 0; dy < 2; ++dy)
#pragma unroll
          for (int dxx = 0; dxx < 2; ++dxx) {
            int pix = b * 3136 + (hp * 2 + dy) * 56 + (wp * 2 + dxx);
            x1g[(size_t)pix * 64 + ch] = x[(size_t)pix * 256 + 192 + ch] + o;
          }
      }
    }
  }
}

// ---------------- Kernel C: fused MLP (weights direct from global) ----------
template <bool NAT>
__device__ __forceinline__ void mlp_body(
    int br, int grp, ushort* sX, ushort* sH,
    const float* __restrict__ x1, const ushort* __restrict__ W1,
    const ushort* __restrict__ W2, const float* __restrict__ B1,
    const float* __restrict__ B2, const float* __restrict__ G,
    const float* __restrict__ Bt, float* __restrict__ out) {
  constexpr int H1 = NAT ? 256 : 192;
  constexpr int K2P = NAT ? 264 : 200;
  constexpr int KB = H1 / 32;
  int tid = threadIdx.x, lane = tid & 63, wid = tid >> 6;
  const float* xin = x1 + ((size_t)br * NPIX + grp * 64) * 64;
  float g = G[lane], bb = Bt[lane];
#pragma unroll
  for (int i = 0; i < 16; ++i) {
    int pl = wid * 16 + i;
    float v = xin[pl * 64 + lane];
    float s1 = wsum(v), s2 = wsum(v * v);
    float m = s1 * (1.f / 64.f);
    float var = s2 * (1.f / 64.f) - m * m;
    sX[pl * 72 + lane] = f2bf((v - m) * rsqrtf(var + 1e-5f) * g + bb);
  }
  __syncthreads();
  int lr = lane & 15, lk = (lane >> 4) * 8;
  int mbase = (wid & 1) * 16;
  int r0 = (lane >> 4) * 4;
  bf16x8 a0[2], a1[2];
#pragma unroll
  for (int mh = 0; mh < 2; ++mh) {
    int m0 = mh * 32 + mbase;
    a0[mh] = *(const bf16x8*)&sX[(m0 + lr) * 72 + lk];
    a1[mh] = *(const bf16x8*)&sX[(m0 + lr) * 72 + 32 + lk];
  }
#pragma unroll
  for (int t2 = 0; t2 < H1 / 32; ++t2) {
    int n0 = ((wid >> 1) + 2 * t2) * 16;
    bf16x8 b0 = *(const bf16x8*)&W1[(n0 + lr) * 72 + lk];
    bf16x8 b1 = *(const bf16x8*)&W1[(n0 + lr) * 72 + 32 + lk];
    int col = n0 + lr;
    float b1v = B1[col];
#pragma unroll
    for (int mh = 0; mh < 2; ++mh) {
      f32x4 acc = {0.f, 0.f, 0.f, 0.f};
      acc = __builtin_amdgcn_mfma_f32_16x16x32_bf16(a0[mh], b0, acc, 0, 0, 0);
      acc = __builtin_amdgcn_mfma_f32_16x16x32_bf16(a1[mh], b1, acc, 0, 0, 0);
      int m0 = mh * 32 + mbase;
#pragma unroll
      for (int r = 0; r < 4; ++r)
        sH[(m0 + r0 + r) * K2P + col] = f2bf(gelu_fast(acc[r] + b1v));
    }
  }
  __syncthreads();
#pragma unroll
  for (int mh = 0; mh < 2; ++mh) {
    int m0 = mh * 32 + mbase;
    bf16x8 af[KB];
#pragma unroll
    for (int kb = 0; kb < KB; ++kb)
      af[kb] = *(const bf16x8*)&sH[(m0 + lr) * K2P + kb * 32 + lk];
#pragma unroll
    for (int u = 0; u < 2; ++u) {
      int n0 = ((wid >> 1) + 2 * u) * 16;
      f32x4 acc = {0.f, 0.f, 0.f, 0.f};
#pragma unroll
      for (int kb = 0; kb < KB; ++kb) {
        bf16x8 bf = *(const bf16x8*)&W2[(n0 + lr) * K2P + kb * 32 + lk];
        acc = __builtin_amdgcn_mfma_f32_16x16x32_bf16(af[kb], bf, acc, 0, 0, 0);
      }
      int col = n0 + lr;
      float b2v = B2[col];
#pragma unroll
      for (int r = 0; r < 4; ++r) {
        int p = m0 + r0 + r;
        int pix = grp * 64 + p;
        out[(size_t)pix * 256 + br * 64 + col] = xin[p * 64 + col] + acc[r] + b2v;
      }
    }
  }
}

__global__ __launch_bounds__(256) void k_mlp(
    const float* __restrict__ x1, const float* __restrict__ nat_ln2_g,
    const float* __restrict__ nat_ln2_b, const ushort* __restrict__ wT,
    const float* __restrict__ nat_f1b, const float* __restrict__ nat_f2b,
    const float* __restrict__ ga_ln2_g, const float* __restrict__ ga_ln2_b,
    const float* __restrict__ ga_f1b, const float* __restrict__ ga_f2b,
    float* __restrict__ out) {
  __shared__ __align__(16) ushort sX[64 * 72];    //  9,216 B
  __shared__ __align__(16) ushort sH[64 * 264];   // 33,792 B  -> 43 KB total
  int bid = blockIdx.x;
  if (bid < 588) {
    int br = bid / 196, grp = bid % 196;
    mlp_body<true>(br, grp, sX, sH, x1, wT + 55296 + br * 18432,
                   wT + 110592 + br * 16896, nat_f1b + br * 256,
                   nat_f2b + br * 64, nat_ln2_g + br * 64, nat_ln2_b + br * 64,
                   out);
  } else {
    int grp = bid - 588;
    mlp_body<false>(3, grp, sX, sH, x1, wT + 175104, wT + 188928, ga_f1b,
                    ga_f2b, ga_ln2_g, ga_ln2_b, out);
  }
}

}  // namespace

extern "C" void kernel_launch(void* const* d_in, const int* in_sizes, int n_in,
                              void* d_out, int out_size, void* d_ws, size_t ws_size,
                              hipStream_t stream) {
  const float* x = (const float*)d_in[0];
  const float* nat_ln1_g = (const float*)d_in[1];
  const float* nat_ln1_b = (const float*)d_in[2];
  const float* nat_qkv_w = (const float*)d_in[3];
  const float* nat_qkv_b = (const float*)d_in[4];
  const float* nat_rpb = (const float*)d_in[5];
  const float* nat_proj_w = (const float*)d_in[6];
  const float* nat_proj_b = (const float*)d_in[7];
  const float* nat_ln2_g = (const float*)d_in[8];
  const float* nat_ln2_b = (const float*)d_in[9];
  const float* nat_fc1_w = (const float*)d_in[10];
  const float* nat_fc1_b = (const float*)d_in[11];
  const float* nat_fc2_w = (const float*)d_in[12];
  const float* nat_fc2_b = (const float*)d_in[13];
  const float* ga_ln1_g = (const float*)d_in[14];
  const float* ga_ln1_b = (const float*)d_in[15];
  const float* ga_qkv_w = (const float*)d_in[16];
  const float* ga_qkv_b = (const float*)d_in[17];
  const float* ga_ln2_g = (const float*)d_in[18];
  const float* ga_ln2_b = (const float*)d_in[19];
  const float* ga_fc1_w = (const float*)d_in[20];
  const float* ga_fc1_b = (const float*)d_in[21];
  const float* ga_fc2_w = (const float*)d_in[22];
  const float* ga_fc2_b = (const float*)d_in[23];

  uint8_t* w8 = (uint8_t*)d_ws;
  ushort* qn  = (ushort*)w8;                  //  4,816,896 B (f16)
  ushort* kvn = (ushort*)(w8 + 4816896);      //  9,633,792 B (f16)
  float*  x1  = (float*)(w8 + 14450688);      // 12,845,056 B
  ushort* wT  = (ushort*)(w8 + 27295744);     //    403,456 B
  ushort* qgb = (ushort*)(w8 + 27699200);     //    409,600 B
  ushort* kgb = (ushort*)(w8 + 28108800);     //    409,600 B
  ushort* vgT = (ushort*)(w8 + 28518400);     //    409,600 B
  // total ~28.9 MB

  k_prep<<<dim3(789), dim3(256), 0, stream>>>(nat_qkv_w, nat_proj_w, nat_fc1_w,
                                              nat_fc2_w, ga_qkv_w, ga_fc1_w,
                                              ga_fc2_w, wT);
  k_qkv<<<dim3(638), dim3(256), 0, stream>>>(x, nat_ln1_g, nat_ln1_b, wT,
                                             nat_qkv_b, qn, kvn, ga_ln1_g,
                                             ga_ln1_b, ga_qkv_b, qgb, kgb, vgT);
  k_attn<<<dim3(688), dim3(256), 0, stream>>>(qn, kvn, nat_rpb, wT, nat_proj_b,
                                              x, x1, qgb, kgb, vgT,
                                              x1 + (size_t)3 * NPIX * 64);
  k_mlp<<<dim3(784), dim3(256), 0, stream>>>(x1, nat_ln2_g, nat_ln2_b, wT,
                                             nat_fc1_b, nat_fc2_b, ga_ln2_g,
                                             ga_ln2_b, ga_fc1_b, ga_fc2_b,
                                             (float*)d_out);
}

// Round 11
// 85.154 us; speedup vs baseline: 1.6014x; 1.0006x over previous
//
#include <hip/hip_runtime.h>
#include <hip/hip_bf16.h>
#include <cstdint>

namespace {

constexpr int NPIX = 12544;   // 4*56*56

typedef __attribute__((ext_vector_type(8))) short bf16x8;
typedef __attribute__((ext_vector_type(4))) float f32x4;
typedef __attribute__((ext_vector_type(16))) float f32x16;
typedef _Float16 h2 __attribute__((ext_vector_type(2)));

__device__ __forceinline__ float wsum(float v) {
#pragma unroll
  for (int m = 32; m; m >>= 1) v += __shfl_xor(v, m, 64);
  return v;
}

__device__ __forceinline__ uint16_t f2bf(float f) {
  uint32_t u = __builtin_bit_cast(uint32_t, f);
  u += 0x7fffu + ((u >> 16) & 1u);
  return (uint16_t)(u >> 16);
}
__device__ __forceinline__ uint32_t packbf(float a, float b) {
  return (uint32_t)f2bf(a) | ((uint32_t)f2bf(b) << 16);
}
__device__ __forceinline__ ushort f2h(float f) {
  _Float16 h = (_Float16)f;
  return __builtin_bit_cast(ushort, h);
}
__device__ __forceinline__ h2 bch2(uint32_t u) { return __builtin_bit_cast(h2, u); }

__device__ __forceinline__ float gelu_fast(float v) {
  float u = 0.7978845608028654f * (v + 0.044715f * v * v * v);
  float e = __expf(2.f * u);
  float th = 1.f - 2.f * __builtin_amdgcn_rcpf(e + 1.f);
  return 0.5f * v * (1.f + th);
}

// ---------------- Prep: convert+transpose all weights to bf16 ----------------
__global__ __launch_bounds__(256) void k_prep(
    const float* __restrict__ nqkv, const float* __restrict__ nproj,
    const float* __restrict__ nf1, const float* __restrict__ nf2,
    const float* __restrict__ gqkv, const float* __restrict__ gf1,
    const float* __restrict__ gf2, ushort* __restrict__ wT) {
  int t = blockIdx.x * 256 + threadIdx.x;
  if (t >= 201728) return;
  int i = t;
  if (i < 41472) {
    int br = i / 13824, r = i % 13824, n = r / 72, k = r % 72;
    wT[t] = k < 64 ? f2bf(nqkv[(br * 64 + k) * 192 + n]) : (ushort)0;
    return;
  }
  i -= 41472;
  if (i < 13824) {
    int br = i / 4608, r = i % 4608, n = r / 72, k = r % 72;
    wT[t] = k < 64 ? f2bf(nproj[(br * 64 + k) * 64 + n]) : (ushort)0;
    return;
  }
  i -= 13824;
  if (i < 55296) {
    int br = i / 18432, r = i % 18432, n = r / 72, k = r % 72;
    wT[t] = k < 64 ? f2bf(nf1[(br * 64 + k) * 256 + n]) : (ushort)0;
    return;
  }
  i -= 55296;
  if (i < 50688) {
    int br = i / 16896, r = i % 16896, n = r / 264, k = r % 264;
    wT[t] = k < 256 ? f2bf(nf2[(br * 256 + k) * 64 + n]) : (ushort)0;
    return;
  }
  i -= 50688;
  if (i < 13824) {
    int n = i / 72, k = i % 72;
    wT[t] = k < 64 ? f2bf(gqkv[k * 192 + n]) : (ushort)0;
    return;
  }
  i -= 13824;
  if (i < 13824) {
    int n = i / 72, k = i % 72;
    wT[t] = k < 64 ? f2bf(gf1[k * 192 + n]) : (ushort)0;
    return;
  }
  i -= 13824;
  {
    int n = i / 200, k = i % 200;
    wT[t] = k < 192 ? f2bf(gf2[k * 64 + n]) : (ushort)0;
  }
}

// ---------------- Kernel A: fused QKV — NAT (0..587) | GA (588..636) | pad (637)
__global__ __launch_bounds__(256) void k_qkv(
    const float* __restrict__ x, const float* __restrict__ nat_ln1_g,
    const float* __restrict__ nat_ln1_b, const ushort* __restrict__ wT,
    const float* __restrict__ nat_qkv_b, ushort* __restrict__ qn,
    ushort* __restrict__ kvn, const float* __restrict__ ga_ln1_g,
    const float* __restrict__ ga_ln1_b, const float* __restrict__ ga_qkv_b,
    ushort* __restrict__ qb, ushort* __restrict__ kb, ushort* __restrict__ vT) {
  __shared__ __align__(16) ushort sA[64 * 72];
  int bid = blockIdx.x;
  int tid = threadIdx.x, lane = tid & 63, wid = tid >> 6;
  if (bid == 637) {
    for (int i = tid; i < 4096; i += 256) {
      int bh = i >> 8, rem = i & 255;
      int n = 784 + (rem >> 4), d = rem & 15;
      qb[((size_t)bh * 800 + n) * 16 + d] = 0;
      kb[((size_t)bh * 800 + n) * 16 + d] = 0;
      vT[((size_t)bh * 16 + d) * 800 + n] = 0;
    }
    return;
  }
  int lr = lane & 15, lk = (lane >> 4) * 8;
  if (bid < 588) {  // NAT LN1 + QKV
    int br = bid / 196, grp = bid % 196;
    const ushort* Wg = wT + br * 13824;
    float g = nat_ln1_g[br * 64 + lane], bb = nat_ln1_b[br * 64 + lane];
#pragma unroll
    for (int i = 0; i < 16; ++i) {
      int pl = wid * 16 + i;
      float v = x[(size_t)(grp * 64 + pl) * 256 + br * 64 + lane];
      float s1 = wsum(v), s2 = wsum(v * v);
      float m = s1 * (1.f / 64.f);
      float var = s2 * (1.f / 64.f) - m * m;
      sA[pl * 72 + lane] = f2bf((v - m) * rsqrtf(var + 1e-5f) * g + bb);
    }
    __syncthreads();
    int m0 = wid * 16;
    bf16x8 a0 = *(const bf16x8*)&sA[(m0 + lr) * 72 + lk];
    bf16x8 a1 = *(const bf16x8*)&sA[(m0 + lr) * 72 + 32 + lk];
    int r0 = m0 + (lane >> 4) * 4;
#pragma unroll
    for (int nt = 0; nt < 12; ++nt) {
      int n0 = nt * 16;
      bf16x8 b0 = *(const bf16x8*)&Wg[(n0 + lr) * 72 + lk];
      bf16x8 b1 = *(const bf16x8*)&Wg[(n0 + lr) * 72 + 32 + lk];
      f32x4 acc = {0.f, 0.f, 0.f, 0.f};
      acc = __builtin_amdgcn_mfma_f32_16x16x32_bf16(a0, b0, acc, 0, 0, 0);
      acc = __builtin_amdgcn_mfma_f32_16x16x32_bf16(a1, b1, acc, 0, 0, 0);
      int col = n0 + lr;
      float bias = nat_qkv_b[br * 192 + col];
      if (nt < 4) {
        ushort* op = qn + ((size_t)br * NPIX + grp * 64 + r0) * 64 + col;
#pragma unroll
        for (int r = 0; r < 4; ++r) op[r * 64] = f2h((acc[r] + bias) * 0.25f);
      } else {
        ushort* op = kvn + ((size_t)br * NPIX + grp * 64 + r0) * 128 + (col - 64);
#pragma unroll
        for (int r = 0; r < 4; ++r) op[r * 128] = f2h(acc[r] + bias);
      }
    }
  } else {  // GA pool+LN + QKV via MFMA (49 blocks x 64 tokens)
    int g64 = bid - 588;
    const ushort* Wg = wT + 161280;
    float gg = ga_ln1_g[lane], bb = ga_ln1_b[lane];
#pragma unroll
    for (int i = 0; i < 16; ++i) {
      int tl = wid * 16 + i;
      int token = g64 * 64 + tl;
      int b = token / 784, rem2 = token % 784, hp = rem2 / 28, wp = rem2 % 28;
      float s = 0.f;
#pragma unroll
      for (int dy = 0; dy < 2; ++dy)
#pragma unroll
        for (int dxx = 0; dxx < 2; ++dxx) {
          int pix = b * 3136 + (hp * 2 + dy) * 56 + (wp * 2 + dxx);
          float v = x[(size_t)pix * 256 + 192 + lane];
          float s1 = wsum(v), s2 = wsum(v * v);
          float m = s1 * (1.f / 64.f);
          float var = s2 * (1.f / 64.f) - m * m;
          s += (v - m) * rsqrtf(var + 1e-5f) * gg + bb;
        }
      sA[tl * 72 + lane] = f2bf(0.25f * s);
    }
    __syncthreads();
    int m0 = wid * 16;
    bf16x8 a0 = *(const bf16x8*)&sA[(m0 + lr) * 72 + lk];
    bf16x8 a1 = *(const bf16x8*)&sA[(m0 + lr) * 72 + 32 + lk];
    int r0 = m0 + (lane >> 4) * 4;
#pragma unroll
    for (int nt = 0; nt < 12; ++nt) {
      int n0 = nt * 16;
      bf16x8 b0 = *(const bf16x8*)&Wg[(n0 + lr) * 72 + lk];
      bf16x8 b1 = *(const bf16x8*)&Wg[(n0 + lr) * 72 + 32 + lk];
      f32x4 acc = {0.f, 0.f, 0.f, 0.f};
      acc = __builtin_amdgcn_mfma_f32_16x16x32_bf16(a0, b0, acc, 0, 0, 0);
      acc = __builtin_amdgcn_mfma_f32_16x16x32_bf16(a1, b1, acc, 0, 0, 0);
      int col = n0 + lr;
      float bias = ga_qkv_b[col];
      int hh = (col & 63) >> 4, d = col & 15;
#pragma unroll
      for (int r = 0; r < 4; ++r) {
        int token = g64 * 64 + r0 + r;
        int b = token / 784, nn = token % 784;
        float v = acc[r] + bias;
        if (col < 64)
          qb[((size_t)(b * 4 + hh) * 800 + nn) * 16 + d] = f2bf(v * 0.25f);
        else if (col < 128)
          kb[((size_t)(b * 4 + hh) * 800 + nn) * 16 + d] = f2bf(v);
        else
          vT[((size_t)(b * 4 + hh) * 16 + d) * 800 + nn] = f2bf(v);
      }
    }
  }
}

// ---------------- Kernel B: fused attention ----------------
// NAT: two-pass softmax, scores in registers; LDS union (halo -> sAp)
__global__ __launch_bounds__(256) void k_attn(
    const ushort* __restrict__ qn, const ushort* __restrict__ kvn,
    const float* __restrict__ rpb, const ushort* __restrict__ wT,
    const float* __restrict__ pb, const float* __restrict__ x,
    float* __restrict__ x1, const ushort* __restrict__ qb,
    const ushort* __restrict__ kb, const ushort* __restrict__ vT,
    float* __restrict__ x1g) {
  __shared__ __align__(16) ushort sBuf[196 * 136];  // 53,312 B -> 3 blocks/CU
  int bid = blockIdx.x;
  int tid = threadIdx.x, lane = tid & 63, wid = tid >> 6;
  if (bid < 588) {
    ushort* sKV = sBuf;
    int br = bid / 196, rem = bid % 196;
    int b = rem / 49, t = rem % 49;
    int y0 = (t / 7) * 8, x0 = (t % 7) * 8;
    int hy = min(max(y0 - 3, 0), 42), hx = min(max(x0 - 3, 0), 42);
    const ushort* kvbase = kvn + ((size_t)br * NPIX + b * 3136) * 128;
    for (int i = tid; i < 3136; i += 256) {
      int p = i >> 4, c = i & 15;
      int py = p / 14, px = p % 14;
      int gp = (hy + py) * 56 + (hx + px);
      uint4 v = *(const uint4*)&kvbase[(size_t)gp * 128 + c * 8];
      *(uint4*)&sKV[p * 136 + c * 8] = v;
    }
    __syncthreads();
    int pl = tid & 63, h = tid >> 6;
    int ly = pl >> 3, lx = pl & 7;
    int y = y0 + ly, xg = x0 + lx;
    int sy = min(max(y - 3, 0), 49), sx = min(max(xg - 3, 0), 49);
    int by = sy - hy, bx = sx - hx;
    int gpix = b * 3136 + y * 56 + xg;
    const ushort* qp = qn + ((size_t)br * NPIX + gpix) * 64 + h * 16;
    uint4 qv0 = *(const uint4*)&qp[0];
    uint4 qv1 = *(const uint4*)&qp[8];
    h2 q[8] = {bch2(qv0.x), bch2(qv0.y), bch2(qv0.z), bch2(qv0.w),
               bch2(qv1.x), bch2(qv1.y), bch2(qv1.z), bch2(qv1.w)};
    const float* rp = rpb + (br * 4 + h) * 169 + (sy - y + 6) * 13 + (sx - xg + 6);
    h2 z = {(_Float16)0.f, (_Float16)0.f};
    // pass 1: all 49 scores into registers + exact max (independent dots)
    float s[49];
    float mx = -1e30f;
#pragma unroll
    for (int a = 0; a < 7; ++a) {
      const ushort* krow = &sKV[((by + a) * 14 + bx) * 136 + h * 16];
      const float* rpa = rp + a * 13;
#pragma unroll
      for (int c = 0; c < 7; ++c) {
        const ushort* kp = krow + c * 136;
        uint4 k0 = *(const uint4*)&kp[0];
        uint4 k1 = *(const uint4*)&kp[8];
        h2 d = z;
        d = bch2(k0.x) * q[0] + d;
        d = bch2(k0.y) * q[1] + d;
        d = bch2(k0.z) * q[2] + d;
        d = bch2(k0.w) * q[3] + d;
        d = bch2(k1.x) * q[4] + d;
        d = bch2(k1.y) * q[5] + d;
        d = bch2(k1.z) * q[6] + d;
        d = bch2(k1.w) * q[7] + d;
        float sd = (float)d[0] + (float)d[1] + rpa[c];
        s[a * 7 + c] = sd;
        mx = fmaxf(mx, sd);
      }
    }
    // pass 2: independent exps + V accumulation (no rescale chain)
    float l = 0.f;
    h2 acc[8];
#pragma unroll
    for (int i = 0; i < 8; ++i) acc[i] = z;
#pragma unroll
    for (int a = 0; a < 7; ++a) {
      const ushort* vrow = &sKV[((by + a) * 14 + bx) * 136 + h * 16 + 64];
#pragma unroll
      for (int c = 0; c < 7; ++c) {
        float p = __expf(s[a * 7 + c] - mx);
        l += p;
        h2 p2 = {(_Float16)p, (_Float16)p};
        const ushort* vp = vrow + c * 136;
        uint4 v0 = *(const uint4*)&vp[0];
        uint4 v1 = *(const uint4*)&vp[8];
        acc[0] = bch2(v0.x) * p2 + acc[0];
        acc[1] = bch2(v0.y) * p2 + acc[1];
        acc[2] = bch2(v0.z) * p2 + acc[2];
        acc[3] = bch2(v0.w) * p2 + acc[3];
        acc[4] = bch2(v1.x) * p2 + acc[4];
        acc[5] = bch2(v1.y) * p2 + acc[5];
        acc[6] = bch2(v1.z) * p2 + acc[6];
        acc[7] = bch2(v1.w) * p2 + acc[7];
      }
    }
    float inv = 1.f / l;
    __syncthreads();  // everyone done reading sKV; repurpose as sAp
    ushort* sAp = sBuf;
    uint32_t* ao = (uint32_t*)&sAp[pl * 72 + h * 16];
#pragma unroll
    for (int i = 0; i < 8; ++i)
      ao[i] = packbf((float)acc[i][0] * inv, (float)acc[i][1] * inv);
    __syncthreads();
    const ushort* Wp = wT + 41472 + br * 4608;
    int lr = lane & 15, lk = (lane >> 4) * 8;
    int m0 = wid * 16;
    bf16x8 a0 = *(const bf16x8*)&sAp[(m0 + lr) * 72 + lk];
    bf16x8 a1 = *(const bf16x8*)&sAp[(m0 + lr) * 72 + 32 + lk];
    int r0 = m0 + (lane >> 4) * 4;
#pragma unroll
    for (int nt = 0; nt < 4; ++nt) {
      int n0 = nt * 16;
      bf16x8 b0 = *(const bf16x8*)&Wp[(n0 + lr) * 72 + lk];
      bf16x8 b1 = *(const bf16x8*)&Wp[(n0 + lr) * 72 + 32 + lk];
      f32x4 oacc = {0.f, 0.f, 0.f, 0.f};
      oacc = __builtin_amdgcn_mfma_f32_16x16x32_bf16(a0, b0, oacc, 0, 0, 0);
      oacc = __builtin_amdgcn_mfma_f32_16x16x32_bf16(a1, b1, oacc, 0, 0, 0);
      int col = n0 + lr;
      float bias = pb[br * 64 + col];
#pragma unroll
      for (int r = 0; r < 4; ++r) {
        int rr = r0 + r;
        int gp2 = b * 3136 + (y0 + (rr >> 3)) * 56 + (x0 + (rr & 7));
        x1[((size_t)br * NPIX + gp2) * 64 + col] =
            oacc[r] + bias + x[(size_t)gp2 * 256 + br * 64 + col];
      }
    }
  } else {
    // GA attention: wave = q-tile
    int wt = (bid - 588) * 4 + wid;
    int bh = wt / 25, qt = wt % 25;
    int h = bh & 3, b = bh >> 2;
    int qrow = lane & 31, hi = lane >> 5;
    int dmod = lane & 15;
    const ushort* qbase = qb + (size_t)bh * 800 * 16;
    const ushort* kbase = kb + (size_t)bh * 800 * 16;
    const ushort* vbase = vT + (size_t)bh * 16 * 800 + (size_t)dmod * 800;
    bf16x8 qf = *(const bf16x8*)&qbase[(qt * 32 + qrow) * 16 + hi * 8];
    float m = -1e30f, l = 0.f;
    f32x16 acc_o;
#pragma unroll
    for (int r = 0; r < 16; ++r) acc_o[r] = 0.f;
    bf16x8 kf = *(const bf16x8*)&kbase[(0 + qrow) * 16 + hi * 8];
    bf16x8 vf0 = *(const bf16x8*)&vbase[0 + hi * 8];
    bf16x8 vf1 = *(const bf16x8*)&vbase[16 + hi * 8];
    for (int kt = 0; kt < 25; ++kt) {
      int nb = (kt < 24 ? kt + 1 : 24) * 32;
      bf16x8 nkf = *(const bf16x8*)&kbase[(nb + qrow) * 16 + hi * 8];
      bf16x8 nvf0 = *(const bf16x8*)&vbase[nb + hi * 8];
      bf16x8 nvf1 = *(const bf16x8*)&vbase[nb + 16 + hi * 8];
      f32x16 zero;
#pragma unroll
      for (int r = 0; r < 16; ++r) zero[r] = 0.f;
      f32x16 st = __builtin_amdgcn_mfma_f32_32x32x16_bf16(kf, qf, zero, 0, 0, 0);
      float s[16];
#pragma unroll
      for (int r = 0; r < 16; ++r) s[r] = st[r];
      if (kt == 24) {
#pragma unroll
        for (int r = 8; r < 16; ++r) s[r] = -1e30f;
      }
      float tm = s[0];
#pragma unroll
      for (int r = 1; r < 16; ++r) tm = fmaxf(tm, s[r]);
      tm = fmaxf(tm, __shfl_xor(tm, 32, 64));
      if (__any(tm > m + 8.f)) {
        float mn = fmaxf(m, tm);
        float sc = __expf(m - mn);
        l *= sc;
        m = mn;
#pragma unroll
        for (int r = 0; r < 16; ++r) {
          int row = (r & 3) + 4 * hi + 8 * (r >> 2);
          float scr = __shfl(sc, row, 64);
          acc_o[r] *= scr;
        }
      }
      uint32_t pk[8];
      float ps = 0.f;
#pragma unroll
      for (int i = 0; i < 8; ++i) {
        float p0 = __expf(s[2 * i] - m), p1 = __expf(s[2 * i + 1] - m);
        ps += p0 + p1;
        pk[i] = packbf(p0, p1);
      }
      l += ps;
#pragma unroll
      for (int t = 0; t < 2; ++t) {
        uint32_t c0 = pk[4 * t + 0], c1 = pk[4 * t + 1];
        uint32_t c2 = pk[4 * t + 2], c3 = pk[4 * t + 3];
        uint32_t b00 = __shfl((int)c0, qrow, 64), b02 = __shfl((int)c2, qrow, 64);
        uint32_t b10 = __shfl((int)c1, qrow, 64), b12 = __shfl((int)c3, qrow, 64);
        uint32_t b20 = __shfl((int)c0, qrow + 32, 64), b22 = __shfl((int)c2, qrow + 32, 64);
        uint32_t b30 = __shfl((int)c1, qrow + 32, 64), b32 = __shfl((int)c3, qrow + 32, 64);
        union { uint32_t u[4]; bf16x8 v; } pa;
        pa.u[0] = hi ? b02 : b00;
        pa.u[1] = hi ? b12 : b10;
        pa.u[2] = hi ? b22 : b20;
        pa.u[3] = hi ? b32 : b30;
        acc_o = __builtin_amdgcn_mfma_f32_32x32x16_bf16(pa.v, (t ? vf1 : vf0),
                                                        acc_o, 0, 0, 0);
      }
      kf = nkf; vf0 = nvf0; vf1 = nvf1;
    }
    l += __shfl_xor(l, 32, 64);
    float inv = 1.f / l;
#pragma unroll
    for (int r = 0; r < 16; ++r) {
      int row = (r & 3) + 4 * hi + 8 * (r >> 2);
      float invr = __shfl(inv, row, 64);
      int n = qt * 32 + row;
      if (n < 784 && qrow < 16) {
        float o = acc_o[r] * invr;
        int hp = n / 28, wp = n % 28;
        int ch = h * 16 + dmod;
#pragma unroll
        for (int dy = 0; dy < 2; ++dy)
#pragma unroll
          for (int dxx = 0; dxx < 2; ++dxx) {
            int pix = b * 3136 + (hp * 2 + dy) * 56 + (wp * 2 + dxx);
            x1g[(size_t)pix * 64 + ch] = x[(size_t)pix * 256 + 192 + ch] + o;
          }
      }
    }
  }
}

// ---------------- Kernel C: fused MLP (weights direct; sH XOR-swizzled) -----
template <bool NAT>
__device__ __forceinline__ void mlp_body(
    int br, int grp, ushort* sX, ushort* sH,
    const float* __restrict__ x1, const ushort* __restrict__ W1,
    const ushort* __restrict__ W2, const float* __restrict__ B1,
    const float* __restrict__ B2, const float* __restrict__ G,
    const float* __restrict__ Bt, float* __restrict__ out) {
  constexpr int H1 = NAT ? 256 : 192;
  constexpr int K2P = NAT ? 264 : 200;
  constexpr int KB = H1 / 32;
  int tid = threadIdx.x, lane = tid & 63, wid = tid >> 6;
  const float* xin = x1 + ((size_t)br * NPIX + grp * 64) * 64;
  float g = G[lane], bb = Bt[lane];
#pragma unroll
  for (int i = 0; i < 16; ++i) {
    int pl = wid * 16 + i;
    float v = xin[pl * 64 + lane];
    float s1 = wsum(v), s2 = wsum(v * v);
    float m = s1 * (1.f / 64.f);
    float var = s2 * (1.f / 64.f) - m * m;
    sX[pl * 72 + lane] = f2bf((v - m) * rsqrtf(var + 1e-5f) * g + bb);
  }
  __syncthreads();
  int lr = lane & 15, lk = (lane >> 4) * 8;
  int mbase = (wid & 1) * 16;
  int r0 = (lane >> 4) * 4;
  bf16x8 a0[2], a1[2];
#pragma unroll
  for (int mh = 0; mh < 2; ++mh) {
    int m0 = mh * 32 + mbase;
    a0[mh] = *(const bf16x8*)&sX[(m0 + lr) * 72 + lk];
    a1[mh] = *(const bf16x8*)&sX[(m0 + lr) * 72 + 32 + lk];
  }
#pragma unroll
  for (int t2 = 0; t2 < H1 / 32; ++t2) {
    int n0 = ((wid >> 1) + 2 * t2) * 16;
    bf16x8 b0 = *(const bf16x8*)&W1[(n0 + lr) * 72 + lk];
    bf16x8 b1 = *(const bf16x8*)&W1[(n0 + lr) * 72 + 32 + lk];
    int col = n0 + lr;
    float b1v = B1[col];
#pragma unroll
    for (int mh = 0; mh < 2; ++mh) {
      f32x4 acc = {0.f, 0.f, 0.f, 0.f};
      acc = __builtin_amdgcn_mfma_f32_16x16x32_bf16(a0[mh], b0, acc, 0, 0, 0);
      acc = __builtin_amdgcn_mfma_f32_16x16x32_bf16(a1[mh], b1, acc, 0, 0, 0);
      int m0 = mh * 32 + mbase;
#pragma unroll
      for (int r = 0; r < 4; ++r) {
        int row = m0 + r0 + r;
        // XOR swizzle keyed on (row>>2)&3: spreads the 4 row-groups of each
        // ds_write across distinct 8-bank blocks (4-way -> 2-way = free)
        sH[row * K2P + (col ^ (((row >> 2) & 3) << 3))] =
            f2bf(gelu_fast(acc[r] + b1v));
      }
    }
  }
  __syncthreads();
#pragma unroll
  for (int mh = 0; mh < 2; ++mh) {
    int m0 = mh * 32 + mbase;
    bf16x8 af[KB];
#pragma unroll
    for (int kb = 0; kb < KB; ++kb) {
      int arow = m0 + lr;
      af[kb] = *(const bf16x8*)&sH[arow * K2P +
                                   ((kb * 32 + lk) ^ (((arow >> 2) & 3) << 3))];
    }
#pragma unroll
    for (int u = 0; u < 2; ++u) {
      int n0 = ((wid >> 1) + 2 * u) * 16;
      f32x4 acc = {0.f, 0.f, 0.f, 0.f};
#pragma unroll
      for (int kb = 0; kb < KB; ++kb) {
        bf16x8 bf = *(const bf16x8*)&W2[(n0 + lr) * K2P + kb * 32 + lk];
        acc = __builtin_amdgcn_mfma_f32_16x16x32_bf16(af[kb], bf, acc, 0, 0, 0);
      }
      int col = n0 + lr;
      float b2v = B2[col];
#pragma unroll
      for (int r = 0; r < 4; ++r) {
        int p = m0 + r0 + r;
        int pix = grp * 64 + p;
        out[(size_t)pix * 256 + br * 64 + col] = xin[p * 64 + col] + acc[r] + b2v;
      }
    }
  }
}

__global__ __launch_bounds__(256) void k_mlp(
    const float* __restrict__ x1, const float* __restrict__ nat_ln2_g,
    const float* __restrict__ nat_ln2_b, const ushort* __restrict__ wT,
    const float* __restrict__ nat_f1b, const float* __restrict__ nat_f2b,
    const float* __restrict__ ga_ln2_g, const float* __restrict__ ga_ln2_b,
    const float* __restrict__ ga_f1b, const float* __restrict__ ga_f2b,
    float* __restrict__ out) {
  __shared__ __align__(16) ushort sX[64 * 72];    //  9,216 B
  __shared__ __align__(16) ushort sH[64 * 264];   // 33,792 B  -> 43 KB total
  int bid = blockIdx.x;
  if (bid < 588) {
    int br = bid / 196, grp = bid % 196;
    mlp_body<true>(br, grp, sX, sH, x1, wT + 55296 + br * 18432,
                   wT + 110592 + br * 16896, nat_f1b + br * 256,
                   nat_f2b + br * 64, nat_ln2_g + br * 64, nat_ln2_b + br * 64,
                   out);
  } else {
    int grp = bid - 588;
    mlp_body<false>(3, grp, sX, sH, x1, wT + 175104, wT + 188928, ga_f1b,
                    ga_f2b, ga_ln2_g, ga_ln2_b, out);
  }
}

}  // namespace

extern "C" void kernel_launch(void* const* d_in, const int* in_sizes, int n_in,
                              void* d_out, int out_size, void* d_ws, size_t ws_size,
                              hipStream_t stream) {
  const float* x = (const float*)d_in[0];
  const float* nat_ln1_g = (const float*)d_in[1];
  const float* nat_ln1_b = (const float*)d_in[2];
  const float* nat_qkv_w = (const float*)d_in[3];
  const float* nat_qkv_b = (const float*)d_in[4];
  const float* nat_rpb = (const float*)d_in[5];
  const float* nat_proj_w = (const float*)d_in[6];
  const float* nat_proj_b = (const float*)d_in[7];
  const float* nat_ln2_g = (const float*)d_in[8];
  const float* nat_ln2_b = (const float*)d_in[9];
  const float* nat_fc1_w = (const float*)d_in[10];
  const float* nat_fc1_b = (const float*)d_in[11];
  const float* nat_fc2_w = (const float*)d_in[12];
  const float* nat_fc2_b = (const float*)d_in[13];
  const float* ga_ln1_g = (const float*)d_in[14];
  const float* ga_ln1_b = (const float*)d_in[15];
  const float* ga_qkv_w = (const float*)d_in[16];
  const float* ga_qkv_b = (const float*)d_in[17];
  const float* ga_ln2_g = (const float*)d_in[18];
  const float* ga_ln2_b = (const float*)d_in[19];
  const float* ga_fc1_w = (const float*)d_in[20];
  const float* ga_fc1_b = (const float*)d_in[21];
  const float* ga_fc2_w = (const float*)d_in[22];
  const float* ga_fc2_b = (const float*)d_in[23];

  uint8_t* w8 = (uint8_t*)d_ws;
  ushort* qn  = (ushort*)w8;                  //  4,816,896 B (f16)
  ushort* kvn = (ushort*)(w8 + 4816896);      //  9,633,792 B (f16)
  float*  x1  = (float*)(w8 + 14450688);      // 12,845,056 B
  ushort* wT  = (ushort*)(w8 + 27295744);     //    403,456 B
  ushort* qgb = (ushort*)(w8 + 27699200);     //    409,600 B
  ushort* kgb = (ushort*)(w8 + 28108800);     //    409,600 B
  ushort* vgT = (ushort*)(w8 + 28518400);     //    409,600 B
  // total ~28.9 MB

  k_prep<<<dim3(789), dim3(256), 0, stream>>>(nat_qkv_w, nat_proj_w, nat_fc1_w,
                                              nat_fc2_w, ga_qkv_w, ga_fc1_w,
                                              ga_fc2_w, wT);
  k_qkv<<<dim3(638), dim3(256), 0, stream>>>(x, nat_ln1_g, nat_ln1_b, wT,
                                             nat_qkv_b, qn, kvn, ga_ln1_g,
                                             ga_ln1_b, ga_qkv_b, qgb, kgb, vgT);
  k_attn<<<dim3(688), dim3(256), 0, stream>>>(qn, kvn, nat_rpb, wT, nat_proj_b,
                                              x, x1, qgb, kgb, vgT,
                                              x1 + (size_t)3 * NPIX * 64);
  k_mlp<<<dim3(784), dim3(256), 0, stream>>>(x1, nat_ln2_g, nat_ln2_b, wT,
                                             nat_fc1_b, nat_fc2_b, ga_ln2_g,
                                             ga_ln2_b, ga_fc1_b, ga_fc2_b,
                                             (float*)d_out);
}